// Round 3
// baseline (135.935 us; speedup 1.0000x reference)
//
#include <hip/hip_runtime.h>
#include <hip/hip_bf16.h>

#define N_NODES 10000
#define N_EDGES 320000
#define HIDDEN 16
#define MSG 64
#define EDGE_FEAT 32
#define KSTEPS 17          // K = 544 = 512 (ef x hidden) + 16 (bias) + 16 (zero pad)
#define KTOT 544

typedef __attribute__((ext_vector_type(8))) short bf16x8;   // 8 x bf16 (4 VGPRs)
typedef __attribute__((ext_vector_type(4))) float f32x4;    // MFMA accumulator

static __device__ __forceinline__ short f2bf(float x) {
    __hip_bfloat16 h = __float2bfloat16(x);
    return *reinterpret_cast<short*>(&h);
}

// ---------------------------------------------------------------------------
// Prep: pack Wr (+bias extension) into per-lane MFMA B-fragment order.
// Wr[k][n] = W[k>>4][n*16 + (k&15)] for k<512; = bias[n*16+(k-512)] for k<528; 0 else.
// B-frag: lane holds k = ks*32 + (lane>>4)*8 + i, n = nt*16 + (lane&15).
// ---------------------------------------------------------------------------
__global__ void prep_wrb(const float* __restrict__ W, const float* __restrict__ bias,
                         ushort* __restrict__ WrB) {
    const int ks   = blockIdx.x;          // 0..16
    const int nt   = threadIdx.x >> 6;    // 0..3
    const int lane = threadIdx.x & 63;
    const int g    = lane >> 4;
    const int n    = nt * 16 + (lane & 15);
    ushort* dst = WrB + (((size_t)ks * 4 + nt) * 64 + lane) * 8;
    #pragma unroll
    for (int i = 0; i < 8; ++i) {
        const int k = ks * 32 + g * 8 + i;
        float v;
        if (k < 512)      v = W[(size_t)(k >> 4) * 1024 + n * 16 + (k & 15)];
        else if (k < 528) v = bias[n * 16 + (k - 512)];
        else              v = 0.0f;
        dst[i] = (ushort)f2bf(v);
    }
}

// ---------------------------------------------------------------------------
// Counting sort by target: histogram -> scan -> scatter
// ---------------------------------------------------------------------------
__global__ void hist_kernel(const int* __restrict__ tgt, int* __restrict__ cnt) {
    const int e = blockIdx.x * 256 + threadIdx.x;
    if (e < N_EDGES) atomicAdd(&cnt[tgt[e]], 1);
}

__global__ __launch_bounds__(1024) void scan_kernel(const int* __restrict__ cnt,
                                                    int* __restrict__ starts,
                                                    int* __restrict__ cursor) {
    __shared__ int ps[1024];
    const int tid = threadIdx.x;
    int c[10];
    int sum = 0;
    #pragma unroll
    for (int j = 0; j < 10; ++j) {
        const int idx = tid * 10 + j;
        c[j] = (idx < N_NODES) ? cnt[idx] : 0;
        sum += c[j];
    }
    ps[tid] = sum;
    __syncthreads();
    #pragma unroll
    for (int off = 1; off < 1024; off <<= 1) {
        int v = (tid >= off) ? ps[tid - off] : 0;
        __syncthreads();
        ps[tid] += v;
        __syncthreads();
    }
    int running = (tid > 0) ? ps[tid - 1] : 0;   // exclusive prefix
    #pragma unroll
    for (int j = 0; j < 10; ++j) {
        const int idx = tid * 10 + j;
        if (idx < N_NODES) {
            starts[idx] = running;
            cursor[idx] = running;
            running += c[j];
        }
    }
    if (tid == 0) starts[N_NODES] = N_EDGES;
}

__global__ void scatter_kernel(const int* __restrict__ tgt, int* __restrict__ cursor,
                               int* __restrict__ perm) {
    const int e = blockIdx.x * 256 + threadIdx.x;
    if (e < N_EDGES) {
        const int pos = atomicAdd(&cursor[tgt[e]], 1);
        perm[pos] = e;
    }
}

// ---------------------------------------------------------------------------
// K1: one wave per node. Gather in-edges, accumulate Zagg[n,k] in fp32 regs:
//   Zagg[n, f*16+h] = sum_e ef[e,f]*hidden[src[e],h];  cols 512..527 = sum_e neigh
// Lane owns k = lane*8 .. lane*8+7  (f = lane>>1, h = (lane&1)*8 + j).
// Write row as bf16 (GEMM A input), cols 528..543 zero.
// ---------------------------------------------------------------------------
__global__ __launch_bounds__(256) void k1_agg(
    const float* __restrict__ ef,      // [E,32]
    const int*   __restrict__ src,     // [E]
    const float* __restrict__ hidden,  // [N,16]
    const int*   __restrict__ perm,
    const int*   __restrict__ starts,
    ushort*      __restrict__ Zagg)    // [N,544] bf16
{
    const int wave = threadIdx.x >> 6;
    const int lane = threadIdx.x & 63;
    const int n    = blockIdx.x * 4 + wave;
    const int s    = starts[n];
    const int e1   = starts[n + 1];
    const int f     = lane >> 1;
    const int hbase = (lane & 1) * 8;

    float zacc[8] = {0.f,0.f,0.f,0.f,0.f,0.f,0.f,0.f};
    float hs[8]   = {0.f,0.f,0.f,0.f,0.f,0.f,0.f,0.f};

    for (int i = s; i < e1; ++i) {
        const int e  = perm[i];
        const int sn = src[e];
        const float efv = ef[(size_t)e * EDGE_FEAT + f];
        const float4* hp = (const float4*)(hidden + (size_t)sn * HIDDEN + hbase);
        const float4 a = hp[0], b = hp[1];
        const float nb[8] = {a.x, a.y, a.z, a.w, b.x, b.y, b.z, b.w};
        #pragma unroll
        for (int j = 0; j < 8; ++j) {
            zacc[j] = fmaf(efv, nb[j], zacc[j]);
            hs[j]  += nb[j];
        }
    }

    bf16x8 z;
    #pragma unroll
    for (int j = 0; j < 8; ++j) z[j] = f2bf(zacc[j]);
    *(bf16x8*)(Zagg + (size_t)n * KTOT + lane * 8) = z;

    if (lane < 4) {
        bf16x8 t;
        #pragma unroll
        for (int j = 0; j < 8; ++j) t[j] = (lane < 2) ? f2bf(hs[j]) : (short)0;
        *(bf16x8*)(Zagg + (size_t)n * KTOT + 512 + lane * 8) = t;
    }
}

// ---------------------------------------------------------------------------
// K2: out[10000,64] = Zagg[10000,544](bf16) @ Wr[544,64](bf16), fp32 out.
// 4 waves/block x 16 rows/wave = 64 rows/block. No atomics - plain stores.
// ---------------------------------------------------------------------------
__global__ __launch_bounds__(256) void k2_gemm(
    const ushort* __restrict__ Zagg,
    const ushort* __restrict__ WrB,
    float*        __restrict__ out)
{
    const int wave = threadIdx.x >> 6;
    const int lane = threadIdx.x & 63;
    const int er   = lane & 15;
    const int g    = lane >> 4;
    const int rowbase = blockIdx.x * 64 + wave * 16;
    const int row  = rowbase + er;
    const int rowc = row < N_NODES ? row : N_NODES - 1;

    const bf16x8* Ap = (const bf16x8*)(Zagg + (size_t)rowc * KTOT);
    const bf16x8* Bp = (const bf16x8*)WrB;

    f32x4 acc0 = {0.f,0.f,0.f,0.f}, acc1 = acc0, acc2 = acc0, acc3 = acc0;
    #pragma unroll
    for (int ks = 0; ks < KSTEPS; ++ks) {
        const bf16x8 af = Ap[ks * 4 + g];
        const bf16x8 b0 = Bp[(ks * 4 + 0) * 64 + lane];
        const bf16x8 b1 = Bp[(ks * 4 + 1) * 64 + lane];
        const bf16x8 b2 = Bp[(ks * 4 + 2) * 64 + lane];
        const bf16x8 b3 = Bp[(ks * 4 + 3) * 64 + lane];
        acc0 = __builtin_amdgcn_mfma_f32_16x16x32_bf16(af, b0, acc0, 0, 0, 0);
        acc1 = __builtin_amdgcn_mfma_f32_16x16x32_bf16(af, b1, acc1, 0, 0, 0);
        acc2 = __builtin_amdgcn_mfma_f32_16x16x32_bf16(af, b2, acc2, 0, 0, 0);
        acc3 = __builtin_amdgcn_mfma_f32_16x16x32_bf16(af, b3, acc3, 0, 0, 0);
    }

    #pragma unroll
    for (int r = 0; r < 4; ++r) {
        const int node = rowbase + g * 4 + r;
        if (node < N_NODES) {
            float* op = out + (size_t)node * MSG;
            op[ 0 + er] = acc0[r];
            op[16 + er] = acc1[r];
            op[32 + er] = acc2[r];
            op[48 + er] = acc3[r];
        }
    }
}

// ---------------------------------------------------------------------------
// Fallback (R2 path): per-edge MFMA + fp32 atomics. Used if ws_size is small.
// ---------------------------------------------------------------------------
__global__ __launch_bounds__(256, 4) void msg_mfma(
    const float* __restrict__ ef, const int* __restrict__ src,
    const int* __restrict__ tgt, const float* __restrict__ hidden,
    const ushort* __restrict__ WrB, float* __restrict__ out)
{
    __shared__ float ef_s[64][36];
    __shared__ float neigh_s[64][20];
    __shared__ int   tgt_s[64];
    const int tid = threadIdx.x;
    const int e0  = blockIdx.x * 64;
    {
        const int e = tid >> 2, h4 = (tid & 3) * 4;
        const int s = src[e0 + e];
        *(float4*)&neigh_s[e][h4] = *(const float4*)(hidden + (size_t)s * HIDDEN + h4);
    }
    {
        const int e = tid >> 2, f8 = (tid & 3) * 8;
        const float* p = ef + (size_t)(e0 + e) * EDGE_FEAT + f8;
        *(float4*)&ef_s[e][f8]     = *(const float4*)(p);
        *(float4*)&ef_s[e][f8 + 4] = *(const float4*)(p + 4);
    }
    if (tid < 64) { ef_s[tid][32] = 1.0f; ef_s[tid][33] = 0.0f; tgt_s[tid] = tgt[e0 + tid]; }
    __syncthreads();
    const int wave = tid >> 6, lane = tid & 63;
    const int er = lane & 15, g = lane >> 4;
    const int e_loc = wave * 16 + er;
    const int h0 = (g & 1) * 8, fg = g >> 1;
    float nb[8];
    #pragma unroll
    for (int j = 0; j < 8; ++j) nb[j] = neigh_s[e_loc][h0 + j];
    f32x4 acc0 = {0.f,0.f,0.f,0.f}, acc1 = acc0, acc2 = acc0, acc3 = acc0;
    const bf16x8* Bp = (const bf16x8*)WrB;
    #pragma unroll
    for (int ks = 0; ks < KSTEPS; ++ks) {
        const float a = ef_s[e_loc][2 * ks + fg];
        bf16x8 af;
        #pragma unroll
        for (int j = 0; j < 8; ++j) af[j] = f2bf(a * nb[j]);
        const bf16x8 b0 = Bp[(ks * 4 + 0) * 64 + lane];
        const bf16x8 b1 = Bp[(ks * 4 + 1) * 64 + lane];
        const bf16x8 b2 = Bp[(ks * 4 + 2) * 64 + lane];
        const bf16x8 b3 = Bp[(ks * 4 + 3) * 64 + lane];
        acc0 = __builtin_amdgcn_mfma_f32_16x16x32_bf16(af, b0, acc0, 0, 0, 0);
        acc1 = __builtin_amdgcn_mfma_f32_16x16x32_bf16(af, b1, acc1, 0, 0, 0);
        acc2 = __builtin_amdgcn_mfma_f32_16x16x32_bf16(af, b2, acc2, 0, 0, 0);
        acc3 = __builtin_amdgcn_mfma_f32_16x16x32_bf16(af, b3, acc3, 0, 0, 0);
    }
    #pragma unroll
    for (int r = 0; r < 4; ++r) {
        const int t = tgt_s[wave * 16 + g * 4 + r];
        float* op = out + (size_t)t * MSG;
        atomicAdd(op +      er, acc0[r]);
        atomicAdd(op + 16 + er, acc1[r]);
        atomicAdd(op + 32 + er, acc2[r]);
        atomicAdd(op + 48 + er, acc3[r]);
    }
}

extern "C" void kernel_launch(void* const* d_in, const int* in_sizes, int n_in,
                              void* d_out, int out_size, void* d_ws, size_t ws_size,
                              hipStream_t stream) {
    // inputs: 0 node_features (unused), 1 edge_features, 2 edge_sources,
    //         3 edge_targets, 4 hidden, 5 initial (unused), 6 W, 7 b
    const float* ef     = (const float*)d_in[1];
    const int*   src    = (const int*)d_in[2];
    const int*   tgt    = (const int*)d_in[3];
    const float* hidden = (const float*)d_in[4];
    const float* W      = (const float*)d_in[6];
    const float* bias   = (const float*)d_in[7];
    float* out = (float*)d_out;
    char*  ws  = (char*)d_ws;

    // ws layout
    const size_t o_wrb    = 0;                         // 69,632 B
    const size_t o_cnt    = 69632;                     // 40,000 B
    const size_t o_starts = o_cnt + 40000;             // 40,004 B
    const size_t o_cursor = o_starts + 40004;          // 40,000 B
    const size_t o_perm   = o_cursor + 40000;          // 1,280,000 B
    const size_t o_zagg   = (o_perm + 1280000 + 15) & ~(size_t)15;  // 10,880,000 B
    const size_t need     = o_zagg + (size_t)N_NODES * KTOT * 2;

    ushort* WrB = (ushort*)(ws + o_wrb);
    prep_wrb<<<KSTEPS, 256, 0, stream>>>(W, bias, WrB);

    if (ws_size >= need) {
        int*    cnt    = (int*)(ws + o_cnt);
        int*    starts = (int*)(ws + o_starts);
        int*    cursor = (int*)(ws + o_cursor);
        int*    perm   = (int*)(ws + o_perm);
        ushort* Zagg   = (ushort*)(ws + o_zagg);

        hipMemsetAsync(cnt, 0, 40000, stream);
        hist_kernel<<<(N_EDGES + 255) / 256, 256, 0, stream>>>(tgt, cnt);
        scan_kernel<<<1, 1024, 0, stream>>>(cnt, starts, cursor);
        scatter_kernel<<<(N_EDGES + 255) / 256, 256, 0, stream>>>(tgt, cursor, perm);
        k1_agg<<<N_NODES / 4, 256, 0, stream>>>(ef, src, hidden, perm, starts, Zagg);
        k2_gemm<<<(N_NODES + 63) / 64, 256, 0, stream>>>(Zagg, WrB, out);
    } else {
        // fallback: per-edge MFMA with fp32 atomics (proven R2 path)
        hipMemsetAsync(out, 0, (size_t)out_size * sizeof(float), stream);
        msg_mfma<<<N_EDGES / 64, 256, 0, stream>>>(ef, src, tgt, hidden, WrB, out);
    }
}

// Round 4
// 107.310 us; speedup vs baseline: 1.2668x; 1.2668x over previous
//
#include <hip/hip_runtime.h>
#include <hip/hip_bf16.h>

#define N_NODES 10000
#define N_EDGES 320000
#define HIDDEN 16
#define MSG 64
#define EDGE_FEAT 32
#define KSTEPS 17          // K = 544 = 512 (ef x hidden) + 16 (bias) + 16 (zero pad)
#define KTOT 544

typedef __attribute__((ext_vector_type(8))) short bf16x8;   // 8 x bf16 (4 VGPRs)
typedef __attribute__((ext_vector_type(4))) float f32x4;    // MFMA accumulator

static __device__ __forceinline__ ushort f2bfu(float x) {
    __hip_bfloat16 h = __float2bfloat16(x);
    return *reinterpret_cast<ushort*>(&h);
}
static __device__ __forceinline__ float bf2f(ushort u) {
    union { float f; unsigned u32; } v; v.u32 = ((unsigned)u) << 16; return v.f;
}

// ---------------------------------------------------------------------------
// Fused: blocks [0,KSTEPS) pack WrB (B-fragments, bias folded at k=512..527);
//        blocks [KSTEPS,...) histogram targets.
// B-frag: lane holds k = ks*32 + (lane>>4)*8 + i, n = nt*16 + (lane&15).
// ---------------------------------------------------------------------------
__global__ void prep_hist(const float* __restrict__ W, const float* __restrict__ bias,
                          const int* __restrict__ tgt,
                          ushort* __restrict__ WrB, int* __restrict__ cnt) {
    if (blockIdx.x < KSTEPS) {
        const int ks   = blockIdx.x;
        const int nt   = threadIdx.x >> 6;
        const int lane = threadIdx.x & 63;
        const int g    = lane >> 4;
        const int n    = nt * 16 + (lane & 15);
        ushort* dst = WrB + (((size_t)ks * 4 + nt) * 64 + lane) * 8;
        #pragma unroll
        for (int i = 0; i < 8; ++i) {
            const int k = ks * 32 + g * 8 + i;
            float v;
            if (k < 512)      v = W[(size_t)(k >> 4) * 1024 + n * 16 + (k & 15)];
            else if (k < 528) v = bias[n * 16 + (k - 512)];
            else              v = 0.0f;
            dst[i] = f2bfu(v);
        }
    } else {
        const int e = (blockIdx.x - KSTEPS) * 256 + threadIdx.x;
        if (e < N_EDGES) atomicAdd(&cnt[tgt[e]], 1);
    }
}

// ---------------------------------------------------------------------------
// Exclusive scan of per-node counts -> starts (and cursor copy)
// ---------------------------------------------------------------------------
__global__ __launch_bounds__(1024) void scan_kernel(const int* __restrict__ cnt,
                                                    int* __restrict__ starts,
                                                    int* __restrict__ cursor) {
    __shared__ int ps[1024];
    const int tid = threadIdx.x;
    int c[10];
    int sum = 0;
    #pragma unroll
    for (int j = 0; j < 10; ++j) {
        const int idx = tid * 10 + j;
        c[j] = (idx < N_NODES) ? cnt[idx] : 0;
        sum += c[j];
    }
    ps[tid] = sum;
    __syncthreads();
    #pragma unroll
    for (int off = 1; off < 1024; off <<= 1) {
        int v = (tid >= off) ? ps[tid - off] : 0;
        __syncthreads();
        ps[tid] += v;
        __syncthreads();
    }
    int running = (tid > 0) ? ps[tid - 1] : 0;
    #pragma unroll
    for (int j = 0; j < 10; ++j) {
        const int idx = tid * 10 + j;
        if (idx < N_NODES) {
            starts[idx] = running;
            cursor[idx] = running;
            running += c[j];
        }
    }
    if (tid == 0) starts[N_NODES] = N_EDGES;
}

// ---------------------------------------------------------------------------
// Scatter-stage: thread per edge. Claim sorted slot, write ef row (bf16) and
// gathered hidden[src] row (bf16) at that slot. All threads independent ->
// gather latency hidden by sheer parallelism. k1 then needs NO indirection.
// ---------------------------------------------------------------------------
__global__ __launch_bounds__(256) void scatter_stage(
    const int*   __restrict__ tgt,
    const int*   __restrict__ src,
    const float* __restrict__ ef,
    const float* __restrict__ hidden,
    int*         __restrict__ cursor,
    ushort*      __restrict__ efs,     // [E][32] bf16, sorted by target
    ushort*      __restrict__ neighs)  // [E][16] bf16, sorted by target
{
    const int e = blockIdx.x * 256 + threadIdx.x;
    if (e >= N_EDGES) return;
    const int t   = tgt[e];
    const int pos = atomicAdd(&cursor[t], 1);

    const float4* ep = (const float4*)(ef + (size_t)e * EDGE_FEAT);
    #pragma unroll
    for (int q = 0; q < 4; ++q) {
        const float4 a = ep[q * 2], b = ep[q * 2 + 1];
        bf16x8 v;
        v[0] = (short)f2bfu(a.x); v[1] = (short)f2bfu(a.y);
        v[2] = (short)f2bfu(a.z); v[3] = (short)f2bfu(a.w);
        v[4] = (short)f2bfu(b.x); v[5] = (short)f2bfu(b.y);
        v[6] = (short)f2bfu(b.z); v[7] = (short)f2bfu(b.w);
        *(bf16x8*)(efs + (size_t)pos * EDGE_FEAT + q * 8) = v;
    }
    const float4* hp = (const float4*)(hidden + (size_t)src[e] * HIDDEN);
    #pragma unroll
    for (int q = 0; q < 2; ++q) {
        const float4 a = hp[q * 2], b = hp[q * 2 + 1];
        bf16x8 v;
        v[0] = (short)f2bfu(a.x); v[1] = (short)f2bfu(a.y);
        v[2] = (short)f2bfu(a.z); v[3] = (short)f2bfu(a.w);
        v[4] = (short)f2bfu(b.x); v[5] = (short)f2bfu(b.y);
        v[6] = (short)f2bfu(b.z); v[7] = (short)f2bfu(b.w);
        *(bf16x8*)(neighs + (size_t)pos * HIDDEN + q * 8) = v;
    }
}

// ---------------------------------------------------------------------------
// K1: one wave per node, PURE STREAMING over its sorted edge range.
// Lane owns k = lane*8..+7  (f = lane>>1, h = (lane&1)*8 + j).
//   Zagg[n, f*16+h] = sum_e ef[e,f]*neigh[e,h];  cols 512..527 = sum_e neigh.
// ---------------------------------------------------------------------------
__global__ __launch_bounds__(256) void k1_stream(
    const ushort* __restrict__ efs,
    const ushort* __restrict__ neighs,
    const int*    __restrict__ starts,
    ushort*       __restrict__ Zagg)   // [N][544] bf16
{
    const int wave = threadIdx.x >> 6;
    const int lane = threadIdx.x & 63;
    const int n    = blockIdx.x * 4 + wave;
    const int s    = starts[n];
    const int e1   = starts[n + 1];
    const int f    = lane >> 1;
    const int hoff = (lane & 1) * 8;

    float zacc[8] = {0.f,0.f,0.f,0.f,0.f,0.f,0.f,0.f};
    float hs[8]   = {0.f,0.f,0.f,0.f,0.f,0.f,0.f,0.f};

    int i = s;
    for (; i + 3 < e1; i += 4) {
        const ushort eu0 = efs[(size_t)(i + 0) * EDGE_FEAT + f];
        const ushort eu1 = efs[(size_t)(i + 1) * EDGE_FEAT + f];
        const ushort eu2 = efs[(size_t)(i + 2) * EDGE_FEAT + f];
        const ushort eu3 = efs[(size_t)(i + 3) * EDGE_FEAT + f];
        const bf16x8 n0 = *(const bf16x8*)(neighs + (size_t)(i + 0) * HIDDEN + hoff);
        const bf16x8 n1 = *(const bf16x8*)(neighs + (size_t)(i + 1) * HIDDEN + hoff);
        const bf16x8 n2 = *(const bf16x8*)(neighs + (size_t)(i + 2) * HIDDEN + hoff);
        const bf16x8 n3 = *(const bf16x8*)(neighs + (size_t)(i + 3) * HIDDEN + hoff);
        const float e0 = bf2f(eu0), e1f = bf2f(eu1), e2 = bf2f(eu2), e3 = bf2f(eu3);
        #pragma unroll
        for (int j = 0; j < 8; ++j) {
            const float a0 = bf2f((ushort)n0[j]);
            const float a1 = bf2f((ushort)n1[j]);
            const float a2 = bf2f((ushort)n2[j]);
            const float a3 = bf2f((ushort)n3[j]);
            zacc[j] = fmaf(e0, a0, zacc[j]);
            zacc[j] = fmaf(e1f, a1, zacc[j]);
            zacc[j] = fmaf(e2, a2, zacc[j]);
            zacc[j] = fmaf(e3, a3, zacc[j]);
            hs[j] += (a0 + a1) + (a2 + a3);
        }
    }
    for (; i < e1; ++i) {
        const ushort eu = efs[(size_t)i * EDGE_FEAT + f];
        const bf16x8 nb = *(const bf16x8*)(neighs + (size_t)i * HIDDEN + hoff);
        const float ev = bf2f(eu);
        #pragma unroll
        for (int j = 0; j < 8; ++j) {
            const float a = bf2f((ushort)nb[j]);
            zacc[j] = fmaf(ev, a, zacc[j]);
            hs[j] += a;
        }
    }

    bf16x8 z;
    #pragma unroll
    for (int j = 0; j < 8; ++j) z[j] = (short)f2bfu(zacc[j]);
    *(bf16x8*)(Zagg + (size_t)n * KTOT + lane * 8) = z;

    if (lane < 4) {
        bf16x8 t;
        #pragma unroll
        for (int j = 0; j < 8; ++j) t[j] = (lane < 2) ? (short)f2bfu(hs[j]) : (short)0;
        *(bf16x8*)(Zagg + (size_t)n * KTOT + 512 + lane * 8) = t;
    }
}

// ---------------------------------------------------------------------------
// K2: out[10000,64] = Zagg[10000,544](bf16) @ Wr[544,64](bf16), fp32 out.
// Plain stores, no atomics.
// ---------------------------------------------------------------------------
__global__ __launch_bounds__(256) void k2_gemm(
    const ushort* __restrict__ Zagg,
    const ushort* __restrict__ WrB,
    float*        __restrict__ out)
{
    const int wave = threadIdx.x >> 6;
    const int lane = threadIdx.x & 63;
    const int er   = lane & 15;
    const int g    = lane >> 4;
    const int rowbase = blockIdx.x * 64 + wave * 16;
    const int row  = rowbase + er;
    const int rowc = row < N_NODES ? row : N_NODES - 1;

    const bf16x8* Ap = (const bf16x8*)(Zagg + (size_t)rowc * KTOT);
    const bf16x8* Bp = (const bf16x8*)WrB;

    f32x4 acc0 = {0.f,0.f,0.f,0.f}, acc1 = acc0, acc2 = acc0, acc3 = acc0;
    #pragma unroll
    for (int ks = 0; ks < KSTEPS; ++ks) {
        const bf16x8 af = Ap[ks * 4 + g];
        const bf16x8 b0 = Bp[(ks * 4 + 0) * 64 + lane];
        const bf16x8 b1 = Bp[(ks * 4 + 1) * 64 + lane];
        const bf16x8 b2 = Bp[(ks * 4 + 2) * 64 + lane];
        const bf16x8 b3 = Bp[(ks * 4 + 3) * 64 + lane];
        acc0 = __builtin_amdgcn_mfma_f32_16x16x32_bf16(af, b0, acc0, 0, 0, 0);
        acc1 = __builtin_amdgcn_mfma_f32_16x16x32_bf16(af, b1, acc1, 0, 0, 0);
        acc2 = __builtin_amdgcn_mfma_f32_16x16x32_bf16(af, b2, acc2, 0, 0, 0);
        acc3 = __builtin_amdgcn_mfma_f32_16x16x32_bf16(af, b3, acc3, 0, 0, 0);
    }

    #pragma unroll
    for (int r = 0; r < 4; ++r) {
        const int node = rowbase + g * 4 + r;
        if (node < N_NODES) {
            float* op = out + (size_t)node * MSG;
            op[ 0 + er] = acc0[r];
            op[16 + er] = acc1[r];
            op[32 + er] = acc2[r];
            op[48 + er] = acc3[r];
        }
    }
}

// ---------------------------------------------------------------------------
// Fallback (R2 path): per-edge MFMA + fp32 atomics. Used if ws_size is small.
// ---------------------------------------------------------------------------
__global__ __launch_bounds__(256, 4) void msg_mfma(
    const float* __restrict__ ef, const int* __restrict__ src,
    const int* __restrict__ tgt, const float* __restrict__ hidden,
    const ushort* __restrict__ WrB, float* __restrict__ out)
{
    __shared__ float ef_s[64][36];
    __shared__ float neigh_s[64][20];
    __shared__ int   tgt_s[64];
    const int tid = threadIdx.x;
    const int e0  = blockIdx.x * 64;
    {
        const int e = tid >> 2, h4 = (tid & 3) * 4;
        const int s = src[e0 + e];
        *(float4*)&neigh_s[e][h4] = *(const float4*)(hidden + (size_t)s * HIDDEN + h4);
    }
    {
        const int e = tid >> 2, f8 = (tid & 3) * 8;
        const float* p = ef + (size_t)(e0 + e) * EDGE_FEAT + f8;
        *(float4*)&ef_s[e][f8]     = *(const float4*)(p);
        *(float4*)&ef_s[e][f8 + 4] = *(const float4*)(p + 4);
    }
    if (tid < 64) { ef_s[tid][32] = 1.0f; ef_s[tid][33] = 0.0f; tgt_s[tid] = tgt[e0 + tid]; }
    __syncthreads();
    const int wave = tid >> 6, lane = tid & 63;
    const int er = lane & 15, g = lane >> 4;
    const int e_loc = wave * 16 + er;
    const int h0 = (g & 1) * 8, fg = g >> 1;
    float nb[8];
    #pragma unroll
    for (int j = 0; j < 8; ++j) nb[j] = neigh_s[e_loc][h0 + j];
    f32x4 acc0 = {0.f,0.f,0.f,0.f}, acc1 = acc0, acc2 = acc0, acc3 = acc0;
    const bf16x8* Bp = (const bf16x8*)WrB;
    #pragma unroll
    for (int ks = 0; ks < KSTEPS; ++ks) {
        const float a = ef_s[e_loc][2 * ks + fg];
        bf16x8 af;
        #pragma unroll
        for (int j = 0; j < 8; ++j) af[j] = (short)f2bfu(a * nb[j]);
        const bf16x8 b0 = Bp[(ks * 4 + 0) * 64 + lane];
        const bf16x8 b1 = Bp[(ks * 4 + 1) * 64 + lane];
        const bf16x8 b2 = Bp[(ks * 4 + 2) * 64 + lane];
        const bf16x8 b3 = Bp[(ks * 4 + 3) * 64 + lane];
        acc0 = __builtin_amdgcn_mfma_f32_16x16x32_bf16(af, b0, acc0, 0, 0, 0);
        acc1 = __builtin_amdgcn_mfma_f32_16x16x32_bf16(af, b1, acc1, 0, 0, 0);
        acc2 = __builtin_amdgcn_mfma_f32_16x16x32_bf16(af, b2, acc2, 0, 0, 0);
        acc3 = __builtin_amdgcn_mfma_f32_16x16x32_bf16(af, b3, acc3, 0, 0, 0);
    }
    #pragma unroll
    for (int r = 0; r < 4; ++r) {
        const int t = tgt_s[wave * 16 + g * 4 + r];
        float* op = out + (size_t)t * MSG;
        atomicAdd(op +      er, acc0[r]);
        atomicAdd(op + 16 + er, acc1[r]);
        atomicAdd(op + 32 + er, acc2[r]);
        atomicAdd(op + 48 + er, acc3[r]);
    }
}

extern "C" void kernel_launch(void* const* d_in, const int* in_sizes, int n_in,
                              void* d_out, int out_size, void* d_ws, size_t ws_size,
                              hipStream_t stream) {
    // inputs: 0 node_features (unused), 1 edge_features, 2 edge_sources,
    //         3 edge_targets, 4 hidden, 5 initial (unused), 6 W, 7 b
    const float* ef     = (const float*)d_in[1];
    const int*   src    = (const int*)d_in[2];
    const int*   tgt    = (const int*)d_in[3];
    const float* hidden = (const float*)d_in[4];
    const float* W      = (const float*)d_in[6];
    const float* bias   = (const float*)d_in[7];
    float* out = (float*)d_out;
    char*  ws  = (char*)d_ws;

    // ws layout (16B-aligned blocks)
    const size_t o_wrb    = 0;                               //    69,632 B
    const size_t o_cnt    = 69632;                           //    40,000 B
    const size_t o_starts = 109632;                          //    40,004 B
    const size_t o_cursor = 149648;                          //    40,000 B
    const size_t o_efs    = 189648;                          // 20,480,000 B
    const size_t o_neighs = o_efs + 20480000;                // 10,240,000 B
    const size_t o_zagg   = o_neighs + 10240000;             // 10,880,000 B
    const size_t need     = o_zagg + (size_t)N_NODES * KTOT * 2;  // ~41.8 MB

    ushort* WrB = (ushort*)(ws + o_wrb);

    if (ws_size >= need) {
        int*    cnt    = (int*)(ws + o_cnt);
        int*    starts = (int*)(ws + o_starts);
        int*    cursor = (int*)(ws + o_cursor);
        ushort* efs    = (ushort*)(ws + o_efs);
        ushort* neighs = (ushort*)(ws + o_neighs);
        ushort* Zagg   = (ushort*)(ws + o_zagg);

        hipMemsetAsync(cnt, 0, 40000, stream);
        prep_hist<<<KSTEPS + (N_EDGES + 255) / 256, 256, 0, stream>>>(W, bias, tgt, WrB, cnt);
        scan_kernel<<<1, 1024, 0, stream>>>(cnt, starts, cursor);
        scatter_stage<<<(N_EDGES + 255) / 256, 256, 0, stream>>>(tgt, src, ef, hidden,
                                                                 cursor, efs, neighs);
        k1_stream<<<N_NODES / 4, 256, 0, stream>>>(efs, neighs, starts, Zagg);
        k2_gemm<<<(N_NODES + 63) / 64, 256, 0, stream>>>(Zagg, WrB, out);
    } else {
        // fallback: per-edge MFMA with fp32 atomics (proven R2 path, 89 us)
        prep_hist<<<KSTEPS, 256, 0, stream>>>(W, bias, tgt, WrB, (int*)(ws + o_cnt));
        hipMemsetAsync(out, 0, (size_t)out_size * sizeof(float), stream);
        msg_mfma<<<N_EDGES / 64, 256, 0, stream>>>(ef, src, tgt, hidden, WrB, out);
    }
}

// Round 5
// 99.966 us; speedup vs baseline: 1.3598x; 1.0735x over previous
//
#include <hip/hip_runtime.h>
#include <hip/hip_bf16.h>

#define N_NODES 10000
#define N_EDGES 320000
#define HIDDEN 16
#define MSG 64
#define EDGE_FEAT 32
#define KSTEPS 17          // K = 544 = 512 (ef x hidden) + 16 (bias) + 16 (zero pad)
#define KTOT 544

typedef __attribute__((ext_vector_type(8))) short bf16x8;   // 8 x bf16 (4 VGPRs)
typedef __attribute__((ext_vector_type(4))) float f32x4;    // MFMA accumulator

static __device__ __forceinline__ ushort f2bfu(float x) {
    __hip_bfloat16 h = __float2bfloat16(x);
    return *reinterpret_cast<ushort*>(&h);
}
static __device__ __forceinline__ float bf2f(ushort u) {
    union { float f; unsigned u32; } v; v.u32 = ((unsigned)u) << 16; return v.f;
}

// ---------------------------------------------------------------------------
// Blocks [0,KSTEPS): pack WrB (B-fragments, bias folded at k=512..527).
// Blocks [KSTEPS,..): rank[e] = atomicAdd(cnt[tgt[e]], 1)  (histogram + rank).
// ---------------------------------------------------------------------------
__global__ void prep_rank(const float* __restrict__ W, const float* __restrict__ bias,
                          const int* __restrict__ tgt,
                          ushort* __restrict__ WrB, int* __restrict__ cnt,
                          int* __restrict__ rank) {
    if (blockIdx.x < KSTEPS) {
        const int ks   = blockIdx.x;
        const int nt   = threadIdx.x >> 6;
        const int lane = threadIdx.x & 63;
        const int g    = lane >> 4;
        const int n    = nt * 16 + (lane & 15);
        ushort* dst = WrB + (((size_t)ks * 4 + nt) * 64 + lane) * 8;
        #pragma unroll
        for (int i = 0; i < 8; ++i) {
            const int k = ks * 32 + g * 8 + i;
            float v;
            if (k < 512)      v = W[(size_t)(k >> 4) * 1024 + n * 16 + (k & 15)];
            else if (k < 528) v = bias[n * 16 + (k - 512)];
            else              v = 0.0f;
            dst[i] = f2bfu(v);
        }
    } else {
        const int e = (blockIdx.x - KSTEPS) * 256 + threadIdx.x;
        if (e < N_EDGES) rank[e] = atomicAdd(&cnt[tgt[e]], 1);
    }
}

// ---------------------------------------------------------------------------
// Exclusive scan of per-node counts -> starts. Wave-shuffle, 2 barriers.
// ---------------------------------------------------------------------------
__global__ __launch_bounds__(1024) void scan_kernel(const int* __restrict__ cnt,
                                                    int* __restrict__ starts) {
    __shared__ int wsum[16];
    __shared__ int wbase[16];
    const int tid  = threadIdx.x;
    const int lane = tid & 63;
    const int wv   = tid >> 6;
    int c[10];
    int s = 0;
    #pragma unroll
    for (int j = 0; j < 10; ++j) {
        const int idx = tid * 10 + j;
        c[j] = (idx < N_NODES) ? cnt[idx] : 0;
        s += c[j];
    }
    int v = s;                               // inclusive scan within wave
    #pragma unroll
    for (int d = 1; d < 64; d <<= 1) {
        const int u = __shfl_up(v, d);
        if (lane >= d) v += u;
    }
    if (lane == 63) wsum[wv] = v;
    __syncthreads();
    if (tid < 16) {
        const int w = wsum[tid];
        int iv = w;
        #pragma unroll
        for (int d = 1; d < 16; d <<= 1) {
            const int u = __shfl_up(iv, d);
            if (tid >= d) iv += u;
        }
        wbase[tid] = iv - w;                 // exclusive wave base
    }
    __syncthreads();
    int running = wbase[wv] + (v - s);       // exclusive prefix for this thread
    #pragma unroll
    for (int j = 0; j < 10; ++j) {
        const int idx = tid * 10 + j;
        if (idx < N_NODES) starts[idx] = running;
        running += c[j];
    }
    if (tid == 1023) starts[N_NODES] = N_EDGES;
}

// ---------------------------------------------------------------------------
// iperm[starts[tgt[e]] + rank[e]] = e   (atomic-free, 4B scattered stores)
// ---------------------------------------------------------------------------
__global__ __launch_bounds__(256) void build_iperm(
    const int* __restrict__ tgt, const int* __restrict__ rank,
    const int* __restrict__ starts, int* __restrict__ iperm) {
    const int e = blockIdx.x * 256 + threadIdx.x;
    if (e < N_EDGES) iperm[starts[tgt[e]] + rank[e]] = e;
}

// ---------------------------------------------------------------------------
// Slot-parallel gather: scattered READS (latency-hidden by 320K independent
// threads), fully COALESCED writes of sorted ef rows (bf16) + src ids.
// ---------------------------------------------------------------------------
__global__ __launch_bounds__(256) void gather_stage(
    const int*   __restrict__ iperm,
    const float* __restrict__ ef,
    const int*   __restrict__ src,
    ushort*      __restrict__ efs,    // [E][32] bf16, sorted by target
    int*         __restrict__ srcs)   // [E], sorted by target
{
    const int slot = blockIdx.x * 256 + threadIdx.x;
    if (slot >= N_EDGES) return;
    const int e = iperm[slot];
    const float4* ep = (const float4*)(ef + (size_t)e * EDGE_FEAT);
    #pragma unroll
    for (int q = 0; q < 4; ++q) {
        const float4 a = ep[q * 2], b = ep[q * 2 + 1];
        bf16x8 v;
        v[0] = (short)f2bfu(a.x); v[1] = (short)f2bfu(a.y);
        v[2] = (short)f2bfu(a.z); v[3] = (short)f2bfu(a.w);
        v[4] = (short)f2bfu(b.x); v[5] = (short)f2bfu(b.y);
        v[6] = (short)f2bfu(b.z); v[7] = (short)f2bfu(b.w);
        *(bf16x8*)(efs + (size_t)slot * EDGE_FEAT + q * 8) = v;
    }
    srcs[slot] = src[e];
}

// ---------------------------------------------------------------------------
// K1: one wave per node, streams sorted efs+srcs; gathers hidden rows from
// L2 (640KB resident, wave-uniform address). Lane owns k = lane*8..+7
// (f = lane>>1, h = (lane&1)*8 + j).
//   Zagg[n, f*16+h] = sum_e ef[e,f]*hidden[src,h];  cols 512..527 = sum hidden.
// ---------------------------------------------------------------------------
__global__ __launch_bounds__(256) void k1_stream(
    const ushort* __restrict__ efs,
    const int*    __restrict__ srcs,
    const float*  __restrict__ hidden,
    const int*    __restrict__ starts,
    ushort*       __restrict__ Zagg)   // [N][544] bf16
{
    const int wave = threadIdx.x >> 6;
    const int lane = threadIdx.x & 63;
    const int n    = blockIdx.x * 4 + wave;
    const int s    = starts[n];
    const int e1   = starts[n + 1];
    const int f    = lane >> 1;
    const int hoff = (lane & 1) * 8;

    float zacc[8] = {0.f,0.f,0.f,0.f,0.f,0.f,0.f,0.f};
    float hs[8]   = {0.f,0.f,0.f,0.f,0.f,0.f,0.f,0.f};

    int i = s;
    for (; i + 3 < e1; i += 4) {
        const ushort eu0 = efs[(size_t)(i + 0) * EDGE_FEAT + f];
        const ushort eu1 = efs[(size_t)(i + 1) * EDGE_FEAT + f];
        const ushort eu2 = efs[(size_t)(i + 2) * EDGE_FEAT + f];
        const ushort eu3 = efs[(size_t)(i + 3) * EDGE_FEAT + f];
        const int s0 = srcs[i + 0], s1 = srcs[i + 1];
        const int s2 = srcs[i + 2], s3 = srcs[i + 3];
        const float4* h0 = (const float4*)(hidden + (size_t)s0 * HIDDEN + hoff);
        const float4* h1 = (const float4*)(hidden + (size_t)s1 * HIDDEN + hoff);
        const float4* h2 = (const float4*)(hidden + (size_t)s2 * HIDDEN + hoff);
        const float4* h3 = (const float4*)(hidden + (size_t)s3 * HIDDEN + hoff);
        const float4 a0 = h0[0], b0 = h0[1];
        const float4 a1 = h1[0], b1 = h1[1];
        const float4 a2 = h2[0], b2 = h2[1];
        const float4 a3 = h3[0], b3 = h3[1];
        const float e0 = bf2f(eu0), e1f = bf2f(eu1), e2 = bf2f(eu2), e3 = bf2f(eu3);
        const float n0[8] = {a0.x,a0.y,a0.z,a0.w,b0.x,b0.y,b0.z,b0.w};
        const float n1[8] = {a1.x,a1.y,a1.z,a1.w,b1.x,b1.y,b1.z,b1.w};
        const float n2[8] = {a2.x,a2.y,a2.z,a2.w,b2.x,b2.y,b2.z,b2.w};
        const float n3[8] = {a3.x,a3.y,a3.z,a3.w,b3.x,b3.y,b3.z,b3.w};
        #pragma unroll
        for (int j = 0; j < 8; ++j) {
            zacc[j] = fmaf(e0,  n0[j], zacc[j]);
            zacc[j] = fmaf(e1f, n1[j], zacc[j]);
            zacc[j] = fmaf(e2,  n2[j], zacc[j]);
            zacc[j] = fmaf(e3,  n3[j], zacc[j]);
            hs[j] += (n0[j] + n1[j]) + (n2[j] + n3[j]);
        }
    }
    for (; i < e1; ++i) {
        const ushort eu = efs[(size_t)i * EDGE_FEAT + f];
        const int sn = srcs[i];
        const float4* hp = (const float4*)(hidden + (size_t)sn * HIDDEN + hoff);
        const float4 a = hp[0], b = hp[1];
        const float nb[8] = {a.x,a.y,a.z,a.w,b.x,b.y,b.z,b.w};
        const float ev = bf2f(eu);
        #pragma unroll
        for (int j = 0; j < 8; ++j) {
            zacc[j] = fmaf(ev, nb[j], zacc[j]);
            hs[j] += nb[j];
        }
    }

    bf16x8 z;
    #pragma unroll
    for (int j = 0; j < 8; ++j) z[j] = (short)f2bfu(zacc[j]);
    *(bf16x8*)(Zagg + (size_t)n * KTOT + lane * 8) = z;

    if (lane < 4) {
        bf16x8 t;
        #pragma unroll
        for (int j = 0; j < 8; ++j) t[j] = (lane < 2) ? (short)f2bfu(hs[j]) : (short)0;
        *(bf16x8*)(Zagg + (size_t)n * KTOT + 512 + lane * 8) = t;
    }
}

// ---------------------------------------------------------------------------
// K2: out[10000,64] = Zagg[10000,544](bf16) @ Wr[544,64](bf16), fp32 out.
// ---------------------------------------------------------------------------
__global__ __launch_bounds__(256) void k2_gemm(
    const ushort* __restrict__ Zagg,
    const ushort* __restrict__ WrB,
    float*        __restrict__ out)
{
    const int wave = threadIdx.x >> 6;
    const int lane = threadIdx.x & 63;
    const int er   = lane & 15;
    const int g    = lane >> 4;
    const int rowbase = blockIdx.x * 64 + wave * 16;
    const int row  = rowbase + er;
    const int rowc = row < N_NODES ? row : N_NODES - 1;

    const bf16x8* Ap = (const bf16x8*)(Zagg + (size_t)rowc * KTOT);
    const bf16x8* Bp = (const bf16x8*)WrB;

    f32x4 acc0 = {0.f,0.f,0.f,0.f}, acc1 = acc0, acc2 = acc0, acc3 = acc0;
    #pragma unroll
    for (int ks = 0; ks < KSTEPS; ++ks) {
        const bf16x8 af = Ap[ks * 4 + g];
        const bf16x8 b0 = Bp[(ks * 4 + 0) * 64 + lane];
        const bf16x8 b1 = Bp[(ks * 4 + 1) * 64 + lane];
        const bf16x8 b2 = Bp[(ks * 4 + 2) * 64 + lane];
        const bf16x8 b3 = Bp[(ks * 4 + 3) * 64 + lane];
        acc0 = __builtin_amdgcn_mfma_f32_16x16x32_bf16(af, b0, acc0, 0, 0, 0);
        acc1 = __builtin_amdgcn_mfma_f32_16x16x32_bf16(af, b1, acc1, 0, 0, 0);
        acc2 = __builtin_amdgcn_mfma_f32_16x16x32_bf16(af, b2, acc2, 0, 0, 0);
        acc3 = __builtin_amdgcn_mfma_f32_16x16x32_bf16(af, b3, acc3, 0, 0, 0);
    }

    #pragma unroll
    for (int r = 0; r < 4; ++r) {
        const int node = rowbase + g * 4 + r;
        if (node < N_NODES) {
            float* op = out + (size_t)node * MSG;
            op[ 0 + er] = acc0[r];
            op[16 + er] = acc1[r];
            op[32 + er] = acc2[r];
            op[48 + er] = acc3[r];
        }
    }
}

// ---------------------------------------------------------------------------
// Fallback (R2 path): per-edge MFMA + fp32 atomics. Used if ws_size is small.
// ---------------------------------------------------------------------------
__global__ __launch_bounds__(256, 4) void msg_mfma(
    const float* __restrict__ ef, const int* __restrict__ src,
    const int* __restrict__ tgt, const float* __restrict__ hidden,
    const ushort* __restrict__ WrB, float* __restrict__ out)
{
    __shared__ float ef_s[64][36];
    __shared__ float neigh_s[64][20];
    __shared__ int   tgt_s[64];
    const int tid = threadIdx.x;
    const int e0  = blockIdx.x * 64;
    {
        const int e = tid >> 2, h4 = (tid & 3) * 4;
        const int s = src[e0 + e];
        *(float4*)&neigh_s[e][h4] = *(const float4*)(hidden + (size_t)s * HIDDEN + h4);
    }
    {
        const int e = tid >> 2, f8 = (tid & 3) * 8;
        const float* p = ef + (size_t)(e0 + e) * EDGE_FEAT + f8;
        *(float4*)&ef_s[e][f8]     = *(const float4*)(p);
        *(float4*)&ef_s[e][f8 + 4] = *(const float4*)(p + 4);
    }
    if (tid < 64) { ef_s[tid][32] = 1.0f; ef_s[tid][33] = 0.0f; tgt_s[tid] = tgt[e0 + tid]; }
    __syncthreads();
    const int wave = tid >> 6, lane = tid & 63;
    const int er = lane & 15, g = lane >> 4;
    const int e_loc = wave * 16 + er;
    const int h0 = (g & 1) * 8, fg = g >> 1;
    float nb[8];
    #pragma unroll
    for (int j = 0; j < 8; ++j) nb[j] = neigh_s[e_loc][h0 + j];
    f32x4 acc0 = {0.f,0.f,0.f,0.f}, acc1 = acc0, acc2 = acc0, acc3 = acc0;
    const bf16x8* Bp = (const bf16x8*)WrB;
    #pragma unroll
    for (int ks = 0; ks < KSTEPS; ++ks) {
        const float a = ef_s[e_loc][2 * ks + fg];
        bf16x8 af;
        #pragma unroll
        for (int j = 0; j < 8; ++j) af[j] = (short)f2bfu(a * nb[j]);
        const bf16x8 b0 = Bp[(ks * 4 + 0) * 64 + lane];
        const bf16x8 b1 = Bp[(ks * 4 + 1) * 64 + lane];
        const bf16x8 b2 = Bp[(ks * 4 + 2) * 64 + lane];
        const bf16x8 b3 = Bp[(ks * 4 + 3) * 64 + lane];
        acc0 = __builtin_amdgcn_mfma_f32_16x16x32_bf16(af, b0, acc0, 0, 0, 0);
        acc1 = __builtin_amdgcn_mfma_f32_16x16x32_bf16(af, b1, acc1, 0, 0, 0);
        acc2 = __builtin_amdgcn_mfma_f32_16x16x32_bf16(af, b2, acc2, 0, 0, 0);
        acc3 = __builtin_amdgcn_mfma_f32_16x16x32_bf16(af, b3, acc3, 0, 0, 0);
    }
    #pragma unroll
    for (int r = 0; r < 4; ++r) {
        const int t = tgt_s[wave * 16 + g * 4 + r];
        float* op = out + (size_t)t * MSG;
        atomicAdd(op +      er, acc0[r]);
        atomicAdd(op + 16 + er, acc1[r]);
        atomicAdd(op + 32 + er, acc2[r]);
        atomicAdd(op + 48 + er, acc3[r]);
    }
}

extern "C" void kernel_launch(void* const* d_in, const int* in_sizes, int n_in,
                              void* d_out, int out_size, void* d_ws, size_t ws_size,
                              hipStream_t stream) {
    // inputs: 0 node_features (unused), 1 edge_features, 2 edge_sources,
    //         3 edge_targets, 4 hidden, 5 initial (unused), 6 W, 7 b
    const float* ef     = (const float*)d_in[1];
    const int*   src    = (const int*)d_in[2];
    const int*   tgt    = (const int*)d_in[3];
    const float* hidden = (const float*)d_in[4];
    const float* W      = (const float*)d_in[6];
    const float* bias   = (const float*)d_in[7];
    float* out = (float*)d_out;
    char*  ws  = (char*)d_ws;

    // ws layout (16B aligned). Aliasing: cnt shares Zagg (cnt dead before k1
    // writes Zagg); rank shares efs (rank dead before gather_stage writes efs).
    const size_t o_wrb    = 0;                                //     69,632 B
    const size_t o_starts = 69632;                            //     40,004 B
    const size_t o_iperm  = 109648;                           //  1,280,000 B
    const size_t o_srcs   = o_iperm + 1280000;                //  1,280,000 B
    const size_t o_zagg   = o_srcs + 1280000;                 // 10,880,000 B (cnt aliases base)
    const size_t o_efs    = o_zagg + (size_t)N_NODES * KTOT * 2;  // 20,480,000 B (rank aliases base)
    const size_t need     = o_efs + (size_t)N_EDGES * EDGE_FEAT * 2;  // ~34.0 MB

    ushort* WrB = (ushort*)(ws + o_wrb);

    if (ws_size >= need) {
        int*    starts = (int*)(ws + o_starts);
        int*    iperm  = (int*)(ws + o_iperm);
        int*    srcs   = (int*)(ws + o_srcs);
        ushort* Zagg   = (ushort*)(ws + o_zagg);
        ushort* efs    = (ushort*)(ws + o_efs);
        int*    cnt    = (int*)(ws + o_zagg);   // alias
        int*    rank   = (int*)(ws + o_efs);    // alias

        hipMemsetAsync(cnt, 0, 40000, stream);
        prep_rank<<<KSTEPS + (N_EDGES + 255) / 256, 256, 0, stream>>>(W, bias, tgt, WrB, cnt, rank);
        scan_kernel<<<1, 1024, 0, stream>>>(cnt, starts);
        build_iperm<<<(N_EDGES + 255) / 256, 256, 0, stream>>>(tgt, rank, starts, iperm);
        gather_stage<<<(N_EDGES + 255) / 256, 256, 0, stream>>>(iperm, ef, src, efs, srcs);
        k1_stream<<<N_NODES / 4, 256, 0, stream>>>(efs, srcs, hidden, starts, Zagg);
        k2_gemm<<<(N_NODES + 63) / 64, 256, 0, stream>>>(Zagg, WrB, out);
    } else {
        // fallback: per-edge MFMA with fp32 atomics (proven R2 path, 89 us)
        prep_rank<<<KSTEPS, 256, 0, stream>>>(W, bias, tgt, WrB, nullptr, nullptr);
        hipMemsetAsync(out, 0, (size_t)out_size * sizeof(float), stream);
        msg_mfma<<<N_EDGES / 64, 256, 0, stream>>>(ef, src, tgt, hidden, WrB, out);
    }
}

// Round 6
// 99.393 us; speedup vs baseline: 1.3677x; 1.0058x over previous
//
#include <hip/hip_runtime.h>
#include <hip/hip_bf16.h>

#define N_NODES 10000
#define N_EDGES 320000
#define HIDDEN 16
#define MSG 64
#define EDGE_FEAT 32
#define KSTEPS 17          // K = 544 = 512 (ef x hidden) + 16 (bias) + 16 (zero pad)
#define KTOT 544

typedef __attribute__((ext_vector_type(8))) short bf16x8;   // 8 x bf16 (4 VGPRs)
typedef __attribute__((ext_vector_type(4))) float f32x4;    // MFMA accumulator

static __device__ __forceinline__ ushort f2bfu(float x) {
    __hip_bfloat16 h = __float2bfloat16(x);
    return *reinterpret_cast<ushort*>(&h);
}
static __device__ __forceinline__ float bf2f(ushort u) {
    union { float f; unsigned u32; } v; v.u32 = ((unsigned)u) << 16; return v.f;
}

// ---------------------------------------------------------------------------
// Blocks [0,KSTEPS): pack WrB (B-fragments, bias folded at k=512..527).
// Blocks [KSTEPS,..): zero cnt (replaces hipMemsetAsync -> rocclr fill, which
// cost ~40us/call in the captured graph).
// ---------------------------------------------------------------------------
__global__ void zero_prep(const float* __restrict__ W, const float* __restrict__ bias,
                          ushort* __restrict__ WrB, int* __restrict__ cnt) {
    if (blockIdx.x < KSTEPS) {
        const int ks   = blockIdx.x;
        const int nt   = threadIdx.x >> 6;
        const int lane = threadIdx.x & 63;
        const int g    = lane >> 4;
        const int n    = nt * 16 + (lane & 15);
        ushort* dst = WrB + (((size_t)ks * 4 + nt) * 64 + lane) * 8;
        #pragma unroll
        for (int i = 0; i < 8; ++i) {
            const int k = ks * 32 + g * 8 + i;
            float v;
            if (k < 512)      v = W[(size_t)(k >> 4) * 1024 + n * 16 + (k & 15)];
            else if (k < 528) v = bias[n * 16 + (k - 512)];
            else              v = 0.0f;
            dst[i] = f2bfu(v);
        }
    } else {
        const int idx = (blockIdx.x - KSTEPS) * 256 + threadIdx.x;
        if (idx < N_NODES) cnt[idx] = 0;
    }
}

// ---------------------------------------------------------------------------
// rank[e] = atomicAdd(cnt[tgt[e]], 1)   (histogram + stable rank in one pass)
// ---------------------------------------------------------------------------
__global__ __launch_bounds__(256) void rank_kernel(const int* __restrict__ tgt,
                                                   int* __restrict__ cnt,
                                                   int* __restrict__ rank) {
    const int e = blockIdx.x * 256 + threadIdx.x;
    if (e < N_EDGES) rank[e] = atomicAdd(&cnt[tgt[e]], 1);
}

// ---------------------------------------------------------------------------
// Exclusive scan of per-node counts -> starts. Wave-shuffle, 2 barriers.
// ---------------------------------------------------------------------------
__global__ __launch_bounds__(1024) void scan_kernel(const int* __restrict__ cnt,
                                                    int* __restrict__ starts) {
    __shared__ int wsum[16];
    __shared__ int wbase[16];
    const int tid  = threadIdx.x;
    const int lane = tid & 63;
    const int wv   = tid >> 6;
    int c[10];
    int s = 0;
    #pragma unroll
    for (int j = 0; j < 10; ++j) {
        const int idx = tid * 10 + j;
        c[j] = (idx < N_NODES) ? cnt[idx] : 0;
        s += c[j];
    }
    int v = s;                               // inclusive scan within wave
    #pragma unroll
    for (int d = 1; d < 64; d <<= 1) {
        const int u = __shfl_up(v, d);
        if (lane >= d) v += u;
    }
    if (lane == 63) wsum[wv] = v;
    __syncthreads();
    if (tid < 16) {
        const int w = wsum[tid];
        int iv = w;
        #pragma unroll
        for (int d = 1; d < 16; d <<= 1) {
            const int u = __shfl_up(iv, d);
            if (tid >= d) iv += u;
        }
        wbase[tid] = iv - w;                 // exclusive wave base
    }
    __syncthreads();
    int running = wbase[wv] + (v - s);       // exclusive prefix for this thread
    #pragma unroll
    for (int j = 0; j < 10; ++j) {
        const int idx = tid * 10 + j;
        if (idx < N_NODES) starts[idx] = running;
        running += c[j];
    }
    if (tid == 1023) starts[N_NODES] = N_EDGES;
}

// ---------------------------------------------------------------------------
// iperm[starts[tgt[e]] + rank[e]] = e   (atomic-free, 4B scattered stores)
// ---------------------------------------------------------------------------
__global__ __launch_bounds__(256) void build_iperm(
    const int* __restrict__ tgt, const int* __restrict__ rank,
    const int* __restrict__ starts, int* __restrict__ iperm) {
    const int e = blockIdx.x * 256 + threadIdx.x;
    if (e < N_EDGES) iperm[starts[tgt[e]] + rank[e]] = e;
}

// ---------------------------------------------------------------------------
// Slot-parallel gather: scattered READS (latency-hidden by 320K independent
// threads), fully COALESCED writes of sorted ef rows (bf16) + src ids.
// ---------------------------------------------------------------------------
__global__ __launch_bounds__(256) void gather_stage(
    const int*   __restrict__ iperm,
    const float* __restrict__ ef,
    const int*   __restrict__ src,
    ushort*      __restrict__ efs,    // [E][32] bf16, sorted by target
    int*         __restrict__ srcs)   // [E], sorted by target
{
    const int slot = blockIdx.x * 256 + threadIdx.x;
    if (slot >= N_EDGES) return;
    const int e = iperm[slot];
    const float4* ep = (const float4*)(ef + (size_t)e * EDGE_FEAT);
    #pragma unroll
    for (int q = 0; q < 4; ++q) {
        const float4 a = ep[q * 2], b = ep[q * 2 + 1];
        bf16x8 v;
        v[0] = (short)f2bfu(a.x); v[1] = (short)f2bfu(a.y);
        v[2] = (short)f2bfu(a.z); v[3] = (short)f2bfu(a.w);
        v[4] = (short)f2bfu(b.x); v[5] = (short)f2bfu(b.y);
        v[6] = (short)f2bfu(b.z); v[7] = (short)f2bfu(b.w);
        *(bf16x8*)(efs + (size_t)slot * EDGE_FEAT + q * 8) = v;
    }
    srcs[slot] = src[e];
}

// ---------------------------------------------------------------------------
// K1: one wave per node, streams sorted efs+srcs; gathers hidden rows from
// L2 (640KB resident). Lane owns k = lane*8..+7 (f = lane>>1, h = (lane&1)*8+j).
//   Zagg[n, f*16+h] = sum_e ef[e,f]*hidden[src,h];  cols 512..527 = sum hidden.
// ---------------------------------------------------------------------------
__global__ __launch_bounds__(256) void k1_stream(
    const ushort* __restrict__ efs,
    const int*    __restrict__ srcs,
    const float*  __restrict__ hidden,
    const int*    __restrict__ starts,
    ushort*       __restrict__ Zagg)   // [N][544] bf16
{
    const int wave = threadIdx.x >> 6;
    const int lane = threadIdx.x & 63;
    const int n    = blockIdx.x * 4 + wave;
    const int s    = starts[n];
    const int e1   = starts[n + 1];
    const int f    = lane >> 1;
    const int hoff = (lane & 1) * 8;

    float zacc[8] = {0.f,0.f,0.f,0.f,0.f,0.f,0.f,0.f};
    float hs[8]   = {0.f,0.f,0.f,0.f,0.f,0.f,0.f,0.f};

    int i = s;
    for (; i + 3 < e1; i += 4) {
        const ushort eu0 = efs[(size_t)(i + 0) * EDGE_FEAT + f];
        const ushort eu1 = efs[(size_t)(i + 1) * EDGE_FEAT + f];
        const ushort eu2 = efs[(size_t)(i + 2) * EDGE_FEAT + f];
        const ushort eu3 = efs[(size_t)(i + 3) * EDGE_FEAT + f];
        const int s0 = srcs[i + 0], s1 = srcs[i + 1];
        const int s2 = srcs[i + 2], s3 = srcs[i + 3];
        const float4* h0 = (const float4*)(hidden + (size_t)s0 * HIDDEN + hoff);
        const float4* h1 = (const float4*)(hidden + (size_t)s1 * HIDDEN + hoff);
        const float4* h2 = (const float4*)(hidden + (size_t)s2 * HIDDEN + hoff);
        const float4* h3 = (const float4*)(hidden + (size_t)s3 * HIDDEN + hoff);
        const float4 a0 = h0[0], b0 = h0[1];
        const float4 a1 = h1[0], b1 = h1[1];
        const float4 a2 = h2[0], b2 = h2[1];
        const float4 a3 = h3[0], b3 = h3[1];
        const float e0 = bf2f(eu0), e1f = bf2f(eu1), e2 = bf2f(eu2), e3 = bf2f(eu3);
        const float n0[8] = {a0.x,a0.y,a0.z,a0.w,b0.x,b0.y,b0.z,b0.w};
        const float n1[8] = {a1.x,a1.y,a1.z,a1.w,b1.x,b1.y,b1.z,b1.w};
        const float n2[8] = {a2.x,a2.y,a2.z,a2.w,b2.x,b2.y,b2.z,b2.w};
        const float n3[8] = {a3.x,a3.y,a3.z,a3.w,b3.x,b3.y,b3.z,b3.w};
        #pragma unroll
        for (int j = 0; j < 8; ++j) {
            zacc[j] = fmaf(e0,  n0[j], zacc[j]);
            zacc[j] = fmaf(e1f, n1[j], zacc[j]);
            zacc[j] = fmaf(e2,  n2[j], zacc[j]);
            zacc[j] = fmaf(e3,  n3[j], zacc[j]);
            hs[j] += (n0[j] + n1[j]) + (n2[j] + n3[j]);
        }
    }
    for (; i < e1; ++i) {
        const ushort eu = efs[(size_t)i * EDGE_FEAT + f];
        const int sn = srcs[i];
        const float4* hp = (const float4*)(hidden + (size_t)sn * HIDDEN + hoff);
        const float4 a = hp[0], b = hp[1];
        const float nb[8] = {a.x,a.y,a.z,a.w,b.x,b.y,b.z,b.w};
        const float ev = bf2f(eu);
        #pragma unroll
        for (int j = 0; j < 8; ++j) {
            zacc[j] = fmaf(ev, nb[j], zacc[j]);
            hs[j] += nb[j];
        }
    }

    bf16x8 z;
    #pragma unroll
    for (int j = 0; j < 8; ++j) z[j] = (short)f2bfu(zacc[j]);
    *(bf16x8*)(Zagg + (size_t)n * KTOT + lane * 8) = z;

    if (lane < 4) {
        bf16x8 t;
        #pragma unroll
        for (int j = 0; j < 8; ++j) t[j] = (lane < 2) ? (short)f2bfu(hs[j]) : (short)0;
        *(bf16x8*)(Zagg + (size_t)n * KTOT + 512 + lane * 8) = t;
    }
}

// ---------------------------------------------------------------------------
// K2: out[10000,64] = Zagg[10000,544](bf16) @ Wr[544,64](bf16), fp32 out.
// ---------------------------------------------------------------------------
__global__ __launch_bounds__(256) void k2_gemm(
    const ushort* __restrict__ Zagg,
    const ushort* __restrict__ WrB,
    float*        __restrict__ out)
{
    const int wave = threadIdx.x >> 6;
    const int lane = threadIdx.x & 63;
    const int er   = lane & 15;
    const int g    = lane >> 4;
    const int rowbase = blockIdx.x * 64 + wave * 16;
    const int row  = rowbase + er;
    const int rowc = row < N_NODES ? row : N_NODES - 1;

    const bf16x8* Ap = (const bf16x8*)(Zagg + (size_t)rowc * KTOT);
    const bf16x8* Bp = (const bf16x8*)WrB;

    f32x4 acc0 = {0.f,0.f,0.f,0.f}, acc1 = acc0, acc2 = acc0, acc3 = acc0;
    #pragma unroll
    for (int ks = 0; ks < KSTEPS; ++ks) {
        const bf16x8 af = Ap[ks * 4 + g];
        const bf16x8 b0 = Bp[(ks * 4 + 0) * 64 + lane];
        const bf16x8 b1 = Bp[(ks * 4 + 1) * 64 + lane];
        const bf16x8 b2 = Bp[(ks * 4 + 2) * 64 + lane];
        const bf16x8 b3 = Bp[(ks * 4 + 3) * 64 + lane];
        acc0 = __builtin_amdgcn_mfma_f32_16x16x32_bf16(af, b0, acc0, 0, 0, 0);
        acc1 = __builtin_amdgcn_mfma_f32_16x16x32_bf16(af, b1, acc1, 0, 0, 0);
        acc2 = __builtin_amdgcn_mfma_f32_16x16x32_bf16(af, b2, acc2, 0, 0, 0);
        acc3 = __builtin_amdgcn_mfma_f32_16x16x32_bf16(af, b3, acc3, 0, 0, 0);
    }

    #pragma unroll
    for (int r = 0; r < 4; ++r) {
        const int node = rowbase + g * 4 + r;
        if (node < N_NODES) {
            float* op = out + (size_t)node * MSG;
            op[ 0 + er] = acc0[r];
            op[16 + er] = acc1[r];
            op[32 + er] = acc2[r];
            op[48 + er] = acc3[r];
        }
    }
}

// ---------------------------------------------------------------------------
// Tiny zero kernel for the fallback path (avoid rocclr fill in graphs).
// ---------------------------------------------------------------------------
__global__ __launch_bounds__(256) void zero_out(float* __restrict__ p, int n4) {
    const int i = blockIdx.x * 256 + threadIdx.x;
    if (i < n4) ((float4*)p)[i] = make_float4(0.f, 0.f, 0.f, 0.f);
}

// ---------------------------------------------------------------------------
// Fallback (R2 path): per-edge MFMA + fp32 atomics. Used if ws_size is small.
// ---------------------------------------------------------------------------
__global__ __launch_bounds__(256, 4) void msg_mfma(
    const float* __restrict__ ef, const int* __restrict__ src,
    const int* __restrict__ tgt, const float* __restrict__ hidden,
    const ushort* __restrict__ WrB, float* __restrict__ out)
{
    __shared__ float ef_s[64][36];
    __shared__ float neigh_s[64][20];
    __shared__ int   tgt_s[64];
    const int tid = threadIdx.x;
    const int e0  = blockIdx.x * 64;
    {
        const int e = tid >> 2, h4 = (tid & 3) * 4;
        const int s = src[e0 + e];
        *(float4*)&neigh_s[e][h4] = *(const float4*)(hidden + (size_t)s * HIDDEN + h4);
    }
    {
        const int e = tid >> 2, f8 = (tid & 3) * 8;
        const float* p = ef + (size_t)(e0 + e) * EDGE_FEAT + f8;
        *(float4*)&ef_s[e][f8]     = *(const float4*)(p);
        *(float4*)&ef_s[e][f8 + 4] = *(const float4*)(p + 4);
    }
    if (tid < 64) { ef_s[tid][32] = 1.0f; ef_s[tid][33] = 0.0f; tgt_s[tid] = tgt[e0 + tid]; }
    __syncthreads();
    const int wave = tid >> 6, lane = tid & 63;
    const int er = lane & 15, g = lane >> 4;
    const int e_loc = wave * 16 + er;
    const int h0 = (g & 1) * 8, fg = g >> 1;
    float nb[8];
    #pragma unroll
    for (int j = 0; j < 8; ++j) nb[j] = neigh_s[e_loc][h0 + j];
    f32x4 acc0 = {0.f,0.f,0.f,0.f}, acc1 = acc0, acc2 = acc0, acc3 = acc0;
    const bf16x8* Bp = (const bf16x8*)WrB;
    #pragma unroll
    for (int ks = 0; ks < KSTEPS; ++ks) {
        const float a = ef_s[e_loc][2 * ks + fg];
        bf16x8 af;
        #pragma unroll
        for (int j = 0; j < 8; ++j) af[j] = (short)f2bfu(a * nb[j]);
        const bf16x8 b0 = Bp[(ks * 4 + 0) * 64 + lane];
        const bf16x8 b1 = Bp[(ks * 4 + 1) * 64 + lane];
        const bf16x8 b2 = Bp[(ks * 4 + 2) * 64 + lane];
        const bf16x8 b3 = Bp[(ks * 4 + 3) * 64 + lane];
        acc0 = __builtin_amdgcn_mfma_f32_16x16x32_bf16(af, b0, acc0, 0, 0, 0);
        acc1 = __builtin_amdgcn_mfma_f32_16x16x32_bf16(af, b1, acc1, 0, 0, 0);
        acc2 = __builtin_amdgcn_mfma_f32_16x16x32_bf16(af, b2, acc2, 0, 0, 0);
        acc3 = __builtin_amdgcn_mfma_f32_16x16x32_bf16(af, b3, acc3, 0, 0, 0);
    }
    #pragma unroll
    for (int r = 0; r < 4; ++r) {
        const int t = tgt_s[wave * 16 + g * 4 + r];
        float* op = out + (size_t)t * MSG;
        atomicAdd(op +      er, acc0[r]);
        atomicAdd(op + 16 + er, acc1[r]);
        atomicAdd(op + 32 + er, acc2[r]);
        atomicAdd(op + 48 + er, acc3[r]);
    }
}

extern "C" void kernel_launch(void* const* d_in, const int* in_sizes, int n_in,
                              void* d_out, int out_size, void* d_ws, size_t ws_size,
                              hipStream_t stream) {
    // inputs: 0 node_features (unused), 1 edge_features, 2 edge_sources,
    //         3 edge_targets, 4 hidden, 5 initial (unused), 6 W, 7 b
    const float* ef     = (const float*)d_in[1];
    const int*   src    = (const int*)d_in[2];
    const int*   tgt    = (const int*)d_in[3];
    const float* hidden = (const float*)d_in[4];
    const float* W      = (const float*)d_in[6];
    const float* bias   = (const float*)d_in[7];
    float* out = (float*)d_out;
    char*  ws  = (char*)d_ws;

    // ws layout (16B aligned). Aliasing: cnt shares Zagg (cnt dead before k1
    // writes Zagg); rank shares efs (rank dead before gather_stage writes efs).
    const size_t o_wrb    = 0;                                //     69,632 B
    const size_t o_starts = 69632;                            //     40,004 B
    const size_t o_iperm  = 109648;                           //  1,280,000 B
    const size_t o_srcs   = o_iperm + 1280000;                //  1,280,000 B
    const size_t o_zagg   = o_srcs + 1280000;                 // 10,880,000 B (cnt aliases base)
    const size_t o_efs    = o_zagg + (size_t)N_NODES * KTOT * 2;  // 20,480,000 B (rank aliases base)
    const size_t need     = o_efs + (size_t)N_EDGES * EDGE_FEAT * 2;  // ~34.0 MB

    ushort* WrB = (ushort*)(ws + o_wrb);

    if (ws_size >= need) {
        int*    starts = (int*)(ws + o_starts);
        int*    iperm  = (int*)(ws + o_iperm);
        int*    srcs   = (int*)(ws + o_srcs);
        ushort* Zagg   = (ushort*)(ws + o_zagg);
        ushort* efs    = (ushort*)(ws + o_efs);
        int*    cnt    = (int*)(ws + o_zagg);   // alias
        int*    rank   = (int*)(ws + o_efs);    // alias

        const int zblocks = (N_NODES + 255) / 256;            // 40
        zero_prep<<<KSTEPS + zblocks, 256, 0, stream>>>(W, bias, WrB, cnt);
        rank_kernel<<<(N_EDGES + 255) / 256, 256, 0, stream>>>(tgt, cnt, rank);
        scan_kernel<<<1, 1024, 0, stream>>>(cnt, starts);
        build_iperm<<<(N_EDGES + 255) / 256, 256, 0, stream>>>(tgt, rank, starts, iperm);
        gather_stage<<<(N_EDGES + 255) / 256, 256, 0, stream>>>(iperm, ef, src, efs, srcs);
        k1_stream<<<N_NODES / 4, 256, 0, stream>>>(efs, srcs, hidden, starts, Zagg);
        k2_gemm<<<(N_NODES + 63) / 64, 256, 0, stream>>>(Zagg, WrB, out);
    } else {
        // fallback: per-edge MFMA with fp32 atomics (proven R2 path, 89 us)
        zero_prep<<<KSTEPS, 256, 0, stream>>>(W, bias, WrB, nullptr);
        const int n4 = out_size / 4;
        zero_out<<<(n4 + 255) / 256, 256, 0, stream>>>(out, n4);
        msg_mfma<<<N_EDGES / 64, 256, 0, stream>>>(ef, src, tgt, hidden, WrB, out);
    }
}

// Round 7
// 98.765 us; speedup vs baseline: 1.3763x; 1.0064x over previous
//
#include <hip/hip_runtime.h>
#include <hip/hip_bf16.h>

#define N_NODES 10000
#define N_EDGES 320000
#define HIDDEN 16
#define MSG 64
#define EDGE_FEAT 32
#define KSTEPS 17          // K = 544 = 512 (ef x hidden) + 16 (bias) + 16 (zero pad)
#define KTOT 544

typedef __attribute__((ext_vector_type(8))) short bf16x8;   // 8 x bf16 (4 VGPRs)
typedef __attribute__((ext_vector_type(4))) float f32x4;    // MFMA accumulator

static __device__ __forceinline__ ushort f2bfu(float x) {
    __hip_bfloat16 h = __float2bfloat16(x);
    return *reinterpret_cast<ushort*>(&h);
}
static __device__ __forceinline__ float bf2f(ushort u) {
    union { float f; unsigned u32; } v; v.u32 = ((unsigned)u) << 16; return v.f;
}

// ---------------------------------------------------------------------------
// Blocks [0,KSTEPS): pack WrB (B-fragments, bias folded at k=512..527).
// Blocks [KSTEPS,..): zero cnt (in-kernel, NOT hipMemsetAsync).
// ---------------------------------------------------------------------------
__global__ void zero_prep(const float* __restrict__ W, const float* __restrict__ bias,
                          ushort* __restrict__ WrB, int* __restrict__ cnt) {
    if (blockIdx.x < KSTEPS) {
        const int ks   = blockIdx.x;
        const int nt   = threadIdx.x >> 6;
        const int lane = threadIdx.x & 63;
        const int g    = lane >> 4;
        const int n    = nt * 16 + (lane & 15);
        ushort* dst = WrB + (((size_t)ks * 4 + nt) * 64 + lane) * 8;
        #pragma unroll
        for (int i = 0; i < 8; ++i) {
            const int k = ks * 32 + g * 8 + i;
            float v;
            if (k < 512)      v = W[(size_t)(k >> 4) * 1024 + n * 16 + (k & 15)];
            else if (k < 528) v = bias[n * 16 + (k - 512)];
            else              v = 0.0f;
            dst[i] = f2bfu(v);
        }
    } else {
        const int idx = (blockIdx.x - KSTEPS) * 256 + threadIdx.x;
        if (idx < N_NODES) cnt[idx] = 0;
    }
}

// ---------------------------------------------------------------------------
// rank[e] = atomicAdd(cnt[tgt[e]], 1)   (histogram + stable rank in one pass)
// ---------------------------------------------------------------------------
__global__ __launch_bounds__(256) void rank_kernel(const int* __restrict__ tgt,
                                                   int* __restrict__ cnt,
                                                   int* __restrict__ rank) {
    const int e = blockIdx.x * 256 + threadIdx.x;
    if (e < N_EDGES) rank[e] = atomicAdd(&cnt[tgt[e]], 1);
}

// ---------------------------------------------------------------------------
// Exclusive scan of per-node counts -> starts. Wave-shuffle, 2 barriers.
// ---------------------------------------------------------------------------
__global__ __launch_bounds__(1024) void scan_kernel(const int* __restrict__ cnt,
                                                    int* __restrict__ starts) {
    __shared__ int wsum[16];
    __shared__ int wbase[16];
    const int tid  = threadIdx.x;
    const int lane = tid & 63;
    const int wv   = tid >> 6;
    int c[10];
    int s = 0;
    #pragma unroll
    for (int j = 0; j < 10; ++j) {
        const int idx = tid * 10 + j;
        c[j] = (idx < N_NODES) ? cnt[idx] : 0;
        s += c[j];
    }
    int v = s;                               // inclusive scan within wave
    #pragma unroll
    for (int d = 1; d < 64; d <<= 1) {
        const int u = __shfl_up(v, d);
        if (lane >= d) v += u;
    }
    if (lane == 63) wsum[wv] = v;
    __syncthreads();
    if (tid < 16) {
        const int w = wsum[tid];
        int iv = w;
        #pragma unroll
        for (int d = 1; d < 16; d <<= 1) {
            const int u = __shfl_up(iv, d);
            if (tid >= d) iv += u;
        }
        wbase[tid] = iv - w;                 // exclusive wave base
    }
    __syncthreads();
    int running = wbase[wv] + (v - s);       // exclusive prefix for this thread
    #pragma unroll
    for (int j = 0; j < 10; ++j) {
        const int idx = tid * 10 + j;
        if (idx < N_NODES) starts[idx] = running;
        running += c[j];
    }
    if (tid == 1023) starts[N_NODES] = N_EDGES;
}

// ---------------------------------------------------------------------------
// Fused sort-placement + staging (replaces build_iperm + gather_stage):
// per edge, pos = starts[tgt[e]] + rank[e]  (no atomic in the chain);
// COALESCED read of ef row (sequential 128B rows), scattered 64B bf16 row
// write + 4B src write. Writes are fire-and-forget -> latency-tolerant.
// ---------------------------------------------------------------------------
__global__ __launch_bounds__(256) void scatter_sorted(
    const int*   __restrict__ tgt,
    const int*   __restrict__ rank,
    const int*   __restrict__ starts,
    const int*   __restrict__ src,
    const float* __restrict__ ef,
    ushort*      __restrict__ efs,    // [E][32] bf16, sorted by target
    int*         __restrict__ srcs)   // [E], sorted by target
{
    const int e = blockIdx.x * 256 + threadIdx.x;
    if (e >= N_EDGES) return;
    const int pos = starts[tgt[e]] + rank[e];

    const float4* ep = (const float4*)(ef + (size_t)e * EDGE_FEAT);
    float4 v[8];
    #pragma unroll
    for (int q = 0; q < 8; ++q) v[q] = ep[q];   // independent coalesced loads

    #pragma unroll
    for (int q = 0; q < 4; ++q) {
        const float4 a = v[2 * q], b = v[2 * q + 1];
        bf16x8 o;
        o[0] = (short)f2bfu(a.x); o[1] = (short)f2bfu(a.y);
        o[2] = (short)f2bfu(a.z); o[3] = (short)f2bfu(a.w);
        o[4] = (short)f2bfu(b.x); o[5] = (short)f2bfu(b.y);
        o[6] = (short)f2bfu(b.z); o[7] = (short)f2bfu(b.w);
        *(bf16x8*)(efs + (size_t)pos * EDGE_FEAT + q * 8) = o;
    }
    srcs[pos] = src[e];
}

// ---------------------------------------------------------------------------
// K1: one wave per node, streams sorted efs+srcs; gathers hidden rows from
// L2 (640KB resident). Lane owns k = lane*8..+7 (f = lane>>1, h = (lane&1)*8+j).
//   Zagg[n, f*16+h] = sum_e ef[e,f]*hidden[src,h];  cols 512..527 = sum hidden.
// ---------------------------------------------------------------------------
__global__ __launch_bounds__(256) void k1_stream(
    const ushort* __restrict__ efs,
    const int*    __restrict__ srcs,
    const float*  __restrict__ hidden,
    const int*    __restrict__ starts,
    ushort*       __restrict__ Zagg)   // [N][544] bf16
{
    const int wave = threadIdx.x >> 6;
    const int lane = threadIdx.x & 63;
    const int n    = blockIdx.x * 4 + wave;
    const int s    = starts[n];
    const int e1   = starts[n + 1];
    const int f    = lane >> 1;
    const int hoff = (lane & 1) * 8;

    float zacc[8] = {0.f,0.f,0.f,0.f,0.f,0.f,0.f,0.f};
    float hs[8]   = {0.f,0.f,0.f,0.f,0.f,0.f,0.f,0.f};

    int i = s;
    for (; i + 3 < e1; i += 4) {
        const ushort eu0 = efs[(size_t)(i + 0) * EDGE_FEAT + f];
        const ushort eu1 = efs[(size_t)(i + 1) * EDGE_FEAT + f];
        const ushort eu2 = efs[(size_t)(i + 2) * EDGE_FEAT + f];
        const ushort eu3 = efs[(size_t)(i + 3) * EDGE_FEAT + f];
        const int s0 = srcs[i + 0], s1 = srcs[i + 1];
        const int s2 = srcs[i + 2], s3 = srcs[i + 3];
        const float4* h0 = (const float4*)(hidden + (size_t)s0 * HIDDEN + hoff);
        const float4* h1 = (const float4*)(hidden + (size_t)s1 * HIDDEN + hoff);
        const float4* h2 = (const float4*)(hidden + (size_t)s2 * HIDDEN + hoff);
        const float4* h3 = (const float4*)(hidden + (size_t)s3 * HIDDEN + hoff);
        const float4 a0 = h0[0], b0 = h0[1];
        const float4 a1 = h1[0], b1 = h1[1];
        const float4 a2 = h2[0], b2 = h2[1];
        const float4 a3 = h3[0], b3 = h3[1];
        const float e0 = bf2f(eu0), e1f = bf2f(eu1), e2 = bf2f(eu2), e3 = bf2f(eu3);
        const float n0[8] = {a0.x,a0.y,a0.z,a0.w,b0.x,b0.y,b0.z,b0.w};
        const float n1[8] = {a1.x,a1.y,a1.z,a1.w,b1.x,b1.y,b1.z,b1.w};
        const float n2[8] = {a2.x,a2.y,a2.z,a2.w,b2.x,b2.y,b2.z,b2.w};
        const float n3[8] = {a3.x,a3.y,a3.z,a3.w,b3.x,b3.y,b3.z,b3.w};
        #pragma unroll
        for (int j = 0; j < 8; ++j) {
            zacc[j] = fmaf(e0,  n0[j], zacc[j]);
            zacc[j] = fmaf(e1f, n1[j], zacc[j]);
            zacc[j] = fmaf(e2,  n2[j], zacc[j]);
            zacc[j] = fmaf(e3,  n3[j], zacc[j]);
            hs[j] += (n0[j] + n1[j]) + (n2[j] + n3[j]);
        }
    }
    for (; i < e1; ++i) {
        const ushort eu = efs[(size_t)i * EDGE_FEAT + f];
        const int sn = srcs[i];
        const float4* hp = (const float4*)(hidden + (size_t)sn * HIDDEN + hoff);
        const float4 a = hp[0], b = hp[1];
        const float nb[8] = {a.x,a.y,a.z,a.w,b.x,b.y,b.z,b.w};
        const float ev = bf2f(eu);
        #pragma unroll
        for (int j = 0; j < 8; ++j) {
            zacc[j] = fmaf(ev, nb[j], zacc[j]);
            hs[j] += nb[j];
        }
    }

    bf16x8 z;
    #pragma unroll
    for (int j = 0; j < 8; ++j) z[j] = (short)f2bfu(zacc[j]);
    *(bf16x8*)(Zagg + (size_t)n * KTOT + lane * 8) = z;

    if (lane < 4) {
        bf16x8 t;
        #pragma unroll
        for (int j = 0; j < 8; ++j) t[j] = (lane < 2) ? (short)f2bfu(hs[j]) : (short)0;
        *(bf16x8*)(Zagg + (size_t)n * KTOT + 512 + lane * 8) = t;
    }
}

// ---------------------------------------------------------------------------
// K2: out[10000,64] = Zagg[10000,544](bf16) @ Wr[544,64](bf16), fp32 out.
// ---------------------------------------------------------------------------
__global__ __launch_bounds__(256) void k2_gemm(
    const ushort* __restrict__ Zagg,
    const ushort* __restrict__ WrB,
    float*        __restrict__ out)
{
    const int wave = threadIdx.x >> 6;
    const int lane = threadIdx.x & 63;
    const int er   = lane & 15;
    const int g    = lane >> 4;
    const int rowbase = blockIdx.x * 64 + wave * 16;
    const int row  = rowbase + er;
    const int rowc = row < N_NODES ? row : N_NODES - 1;

    const bf16x8* Ap = (const bf16x8*)(Zagg + (size_t)rowc * KTOT);
    const bf16x8* Bp = (const bf16x8*)WrB;

    f32x4 acc0 = {0.f,0.f,0.f,0.f}, acc1 = acc0, acc2 = acc0, acc3 = acc0;
    #pragma unroll
    for (int ks = 0; ks < KSTEPS; ++ks) {
        const bf16x8 af = Ap[ks * 4 + g];
        const bf16x8 b0 = Bp[(ks * 4 + 0) * 64 + lane];
        const bf16x8 b1 = Bp[(ks * 4 + 1) * 64 + lane];
        const bf16x8 b2 = Bp[(ks * 4 + 2) * 64 + lane];
        const bf16x8 b3 = Bp[(ks * 4 + 3) * 64 + lane];
        acc0 = __builtin_amdgcn_mfma_f32_16x16x32_bf16(af, b0, acc0, 0, 0, 0);
        acc1 = __builtin_amdgcn_mfma_f32_16x16x32_bf16(af, b1, acc1, 0, 0, 0);
        acc2 = __builtin_amdgcn_mfma_f32_16x16x32_bf16(af, b2, acc2, 0, 0, 0);
        acc3 = __builtin_amdgcn_mfma_f32_16x16x32_bf16(af, b3, acc3, 0, 0, 0);
    }

    #pragma unroll
    for (int r = 0; r < 4; ++r) {
        const int node = rowbase + g * 4 + r;
        if (node < N_NODES) {
            float* op = out + (size_t)node * MSG;
            op[ 0 + er] = acc0[r];
            op[16 + er] = acc1[r];
            op[32 + er] = acc2[r];
            op[48 + er] = acc3[r];
        }
    }
}

// ---------------------------------------------------------------------------
// Tiny zero kernel for the fallback path (avoid rocclr fill in graphs).
// ---------------------------------------------------------------------------
__global__ __launch_bounds__(256) void zero_out(float* __restrict__ p, int n4) {
    const int i = blockIdx.x * 256 + threadIdx.x;
    if (i < n4) ((float4*)p)[i] = make_float4(0.f, 0.f, 0.f, 0.f);
}

// ---------------------------------------------------------------------------
// Fallback (R2 path): per-edge MFMA + fp32 atomics. Used if ws_size is small.
// ---------------------------------------------------------------------------
__global__ __launch_bounds__(256, 4) void msg_mfma(
    const float* __restrict__ ef, const int* __restrict__ src,
    const int* __restrict__ tgt, const float* __restrict__ hidden,
    const ushort* __restrict__ WrB, float* __restrict__ out)
{
    __shared__ float ef_s[64][36];
    __shared__ float neigh_s[64][20];
    __shared__ int   tgt_s[64];
    const int tid = threadIdx.x;
    const int e0  = blockIdx.x * 64;
    {
        const int e = tid >> 2, h4 = (tid & 3) * 4;
        const int s = src[e0 + e];
        *(float4*)&neigh_s[e][h4] = *(const float4*)(hidden + (size_t)s * HIDDEN + h4);
    }
    {
        const int e = tid >> 2, f8 = (tid & 3) * 8;
        const float* p = ef + (size_t)(e0 + e) * EDGE_FEAT + f8;
        *(float4*)&ef_s[e][f8]     = *(const float4*)(p);
        *(float4*)&ef_s[e][f8 + 4] = *(const float4*)(p + 4);
    }
    if (tid < 64) { ef_s[tid][32] = 1.0f; ef_s[tid][33] = 0.0f; tgt_s[tid] = tgt[e0 + tid]; }
    __syncthreads();
    const int wave = tid >> 6, lane = tid & 63;
    const int er = lane & 15, g = lane >> 4;
    const int e_loc = wave * 16 + er;
    const int h0 = (g & 1) * 8, fg = g >> 1;
    float nb[8];
    #pragma unroll
    for (int j = 0; j < 8; ++j) nb[j] = neigh_s[e_loc][h0 + j];
    f32x4 acc0 = {0.f,0.f,0.f,0.f}, acc1 = acc0, acc2 = acc0, acc3 = acc0;
    const bf16x8* Bp = (const bf16x8*)WrB;
    #pragma unroll
    for (int ks = 0; ks < KSTEPS; ++ks) {
        const float a = ef_s[e_loc][2 * ks + fg];
        bf16x8 af;
        #pragma unroll
        for (int j = 0; j < 8; ++j) af[j] = (short)f2bfu(a * nb[j]);
        const bf16x8 b0 = Bp[(ks * 4 + 0) * 64 + lane];
        const bf16x8 b1 = Bp[(ks * 4 + 1) * 64 + lane];
        const bf16x8 b2 = Bp[(ks * 4 + 2) * 64 + lane];
        const bf16x8 b3 = Bp[(ks * 4 + 3) * 64 + lane];
        acc0 = __builtin_amdgcn_mfma_f32_16x16x32_bf16(af, b0, acc0, 0, 0, 0);
        acc1 = __builtin_amdgcn_mfma_f32_16x16x32_bf16(af, b1, acc1, 0, 0, 0);
        acc2 = __builtin_amdgcn_mfma_f32_16x16x32_bf16(af, b2, acc2, 0, 0, 0);
        acc3 = __builtin_amdgcn_mfma_f32_16x16x32_bf16(af, b3, acc3, 0, 0, 0);
    }
    #pragma unroll
    for (int r = 0; r < 4; ++r) {
        const int t = tgt_s[wave * 16 + g * 4 + r];
        float* op = out + (size_t)t * MSG;
        atomicAdd(op +      er, acc0[r]);
        atomicAdd(op + 16 + er, acc1[r]);
        atomicAdd(op + 32 + er, acc2[r]);
        atomicAdd(op + 48 + er, acc3[r]);
    }
}

extern "C" void kernel_launch(void* const* d_in, const int* in_sizes, int n_in,
                              void* d_out, int out_size, void* d_ws, size_t ws_size,
                              hipStream_t stream) {
    // inputs: 0 node_features (unused), 1 edge_features, 2 edge_sources,
    //         3 edge_targets, 4 hidden, 5 initial (unused), 6 W, 7 b
    const float* ef     = (const float*)d_in[1];
    const int*   src    = (const int*)d_in[2];
    const int*   tgt    = (const int*)d_in[3];
    const float* hidden = (const float*)d_in[4];
    const float* W      = (const float*)d_in[6];
    const float* bias   = (const float*)d_in[7];
    float* out = (float*)d_out;
    char*  ws  = (char*)d_ws;

    // ws layout — plain, no aliasing (ws_size is 256 MiB; need ~34.1 MB)
    const size_t o_wrb    = 0;            //     69,632 B
    const size_t o_starts = 69632;        //     40,004 B
    const size_t o_cnt    = 109648;       //     40,000 B
    const size_t o_rank   = 149648;       //  1,280,000 B
    const size_t o_srcs   = 1429648;      //  1,280,000 B
    const size_t o_efs    = 2709648;      // 20,480,000 B
    const size_t o_zagg   = 23189648;     // 10,880,000 B
    const size_t need     = o_zagg + (size_t)N_NODES * KTOT * 2;   // ~34.07 MB

    ushort* WrB = (ushort*)(ws + o_wrb);

    if (ws_size >= need) {
        int*    starts = (int*)(ws + o_starts);
        int*    cnt    = (int*)(ws + o_cnt);
        int*    rank   = (int*)(ws + o_rank);
        int*    srcs   = (int*)(ws + o_srcs);
        ushort* efs    = (ushort*)(ws + o_efs);
        ushort* Zagg   = (ushort*)(ws + o_zagg);

        const int zblocks = (N_NODES + 255) / 256;            // 40
        zero_prep<<<KSTEPS + zblocks, 256, 0, stream>>>(W, bias, WrB, cnt);
        rank_kernel<<<(N_EDGES + 255) / 256, 256, 0, stream>>>(tgt, cnt, rank);
        scan_kernel<<<1, 1024, 0, stream>>>(cnt, starts);
        scatter_sorted<<<(N_EDGES + 255) / 256, 256, 0, stream>>>(tgt, rank, starts,
                                                                  src, ef, efs, srcs);
        k1_stream<<<N_NODES / 4, 256, 0, stream>>>(efs, srcs, hidden, starts, Zagg);
        k2_gemm<<<(N_NODES + 63) / 64, 256, 0, stream>>>(Zagg, WrB, out);
    } else {
        // fallback: per-edge MFMA with fp32 atomics (proven R2 path, 89 us)
        zero_prep<<<KSTEPS, 256, 0, stream>>>(W, bias, WrB, nullptr);
        const int n4 = out_size / 4;
        zero_out<<<(n4 + 255) / 256, 256, 0, stream>>>(out, n4);
        msg_mfma<<<N_EDGES / 64, 256, 0, stream>>>(ef, src, tgt, hidden, WrB, out);
    }
}

// Round 8
// 89.981 us; speedup vs baseline: 1.5107x; 1.0976x over previous
//
#include <hip/hip_runtime.h>
#include <hip/hip_bf16.h>

#define N_NODES 10000
#define N_EDGES 320000
#define HIDDEN 16
#define MSG 64
#define EDGE_FEAT 32
#define KSTEPS 17          // K = 544 = 512 (ef x hidden) + 16 (bias) + 16 (zero pad)
#define KTOT 544

typedef __attribute__((ext_vector_type(8))) short bf16x8;   // 8 x bf16 (4 VGPRs)
typedef __attribute__((ext_vector_type(4))) float f32x4;    // MFMA accumulator

static __device__ __forceinline__ ushort f2bfu(float x) {
    __hip_bfloat16 h = __float2bfloat16(x);
    return *reinterpret_cast<ushort*>(&h);
}

// ---------------------------------------------------------------------------
// Blocks [0,KSTEPS): pack WrB (B-fragments, bias folded at k=512..527).
// Blocks [KSTEPS, KSTEPS+40): zero cnt.   Blocks [KSTEPS+40, ...): zero out.
// (all in-kernel zeroing - no hipMemsetAsync / rocclr fill in the graph)
// ---------------------------------------------------------------------------
__global__ void zero_prep(const float* __restrict__ W, const float* __restrict__ bias,
                          ushort* __restrict__ WrB, int* __restrict__ cnt,
                          float4* __restrict__ out4, int n4) {
    if (blockIdx.x < KSTEPS) {
        const int ks   = blockIdx.x;
        const int nt   = threadIdx.x >> 6;
        const int lane = threadIdx.x & 63;
        const int g    = lane >> 4;
        const int n    = nt * 16 + (lane & 15);
        ushort* dst = WrB + (((size_t)ks * 4 + nt) * 64 + lane) * 8;
        #pragma unroll
        for (int i = 0; i < 8; ++i) {
            const int k = ks * 32 + g * 8 + i;
            float v;
            if (k < 512)      v = W[(size_t)(k >> 4) * 1024 + n * 16 + (k & 15)];
            else if (k < 528) v = bias[n * 16 + (k - 512)];
            else              v = 0.0f;
            dst[i] = f2bfu(v);
        }
    } else if (blockIdx.x < KSTEPS + 40) {
        const int idx = (blockIdx.x - KSTEPS) * 256 + threadIdx.x;
        if (idx < N_NODES) cnt[idx] = 0;
    } else {
        const int i = (blockIdx.x - KSTEPS - 40) * 256 + threadIdx.x;
        if (i < n4) out4[i] = make_float4(0.f, 0.f, 0.f, 0.f);
    }
}

// ---------------------------------------------------------------------------
// rank[e] = atomicAdd(cnt[tgt[e]], 1)   (histogram + stable rank in one pass)
// ---------------------------------------------------------------------------
__global__ __launch_bounds__(256) void rank_kernel(const int* __restrict__ tgt,
                                                   int* __restrict__ cnt,
                                                   int* __restrict__ rank) {
    const int e = blockIdx.x * 256 + threadIdx.x;
    if (e < N_EDGES) rank[e] = atomicAdd(&cnt[tgt[e]], 1);
}

// ---------------------------------------------------------------------------
// Exclusive scan of per-node counts -> starts. Wave-shuffle, 2 barriers.
// ---------------------------------------------------------------------------
__global__ __launch_bounds__(1024) void scan_kernel(const int* __restrict__ cnt,
                                                    int* __restrict__ starts) {
    __shared__ int wsum[16];
    __shared__ int wbase[16];
    const int tid  = threadIdx.x;
    const int lane = tid & 63;
    const int wv   = tid >> 6;
    int c[10];
    int s = 0;
    #pragma unroll
    for (int j = 0; j < 10; ++j) {
        const int idx = tid * 10 + j;
        c[j] = (idx < N_NODES) ? cnt[idx] : 0;
        s += c[j];
    }
    int v = s;                               // inclusive scan within wave
    #pragma unroll
    for (int d = 1; d < 64; d <<= 1) {
        const int u = __shfl_up(v, d);
        if (lane >= d) v += u;
    }
    if (lane == 63) wsum[wv] = v;
    __syncthreads();
    if (tid < 16) {
        const int w = wsum[tid];
        int iv = w;
        #pragma unroll
        for (int d = 1; d < 16; d <<= 1) {
            const int u = __shfl_up(iv, d);
            if (tid >= d) iv += u;
        }
        wbase[tid] = iv - w;                 // exclusive wave base
    }
    __syncthreads();
    int running = wbase[wv] + (v - s);       // exclusive prefix for this thread
    #pragma unroll
    for (int j = 0; j < 10; ++j) {
        const int idx = tid * 10 + j;
        if (idx < N_NODES) starts[idx] = running;
        running += c[j];
    }
    if (tid == 1023) starts[N_NODES] = N_EDGES;
}

// ---------------------------------------------------------------------------
// iperm[starts[tgt[e]] + rank[e]] = e   (atomic-free, 4B scattered stores)
// ---------------------------------------------------------------------------
__global__ __launch_bounds__(256) void build_iperm(
    const int* __restrict__ tgt, const int* __restrict__ rank,
    const int* __restrict__ starts, int* __restrict__ iperm) {
    const int e = blockIdx.x * 256 + threadIdx.x;
    if (e < N_EDGES) iperm[starts[tgt[e]] + rank[e]] = e;
}

// ---------------------------------------------------------------------------
// Fused: per block, 64 TARGET-SORTED edges (via iperm). Gather ef/hidden into
// LDS, MFMA the 64x64 message tile (R2 structure), store tile to LDS, then
// wave-uniform run-length segmented reduction down the edge axis ->
// ~2-4 distinct targets per block -> ~1.9M atomics total (11x fewer than R2).
// ---------------------------------------------------------------------------
__global__ __launch_bounds__(256) void fused_msg(
    const int*    __restrict__ iperm,
    const int*    __restrict__ tgt,
    const int*    __restrict__ src,
    const float*  __restrict__ ef,
    const float*  __restrict__ hidden,
    const ushort* __restrict__ WrB,
    float*        __restrict__ out)
{
    __shared__ float ef_s[64][36];     // cols 0..31 ef, 32 = 1.0 (bias), 33 = 0.0
    __shared__ float neigh_s[64][20];
    __shared__ int   tgt_s[64];
    __shared__ float msg_s[64][68];    // message tile, padded

    const int tid = threadIdx.x;
    const int s0  = blockIdx.x * 64;

    // gather phase: quad of threads per sorted slot
    const int e = iperm[s0 + (tid >> 2)];
    {
        const int h4 = (tid & 3) * 4;
        const int sn = src[e];
        *(float4*)&neigh_s[tid >> 2][h4] = *(const float4*)(hidden + (size_t)sn * HIDDEN + h4);
    }
    {
        const int f8 = (tid & 3) * 8;
        const float* p = ef + (size_t)e * EDGE_FEAT + f8;
        *(float4*)&ef_s[tid >> 2][f8]     = *(const float4*)(p);
        *(float4*)&ef_s[tid >> 2][f8 + 4] = *(const float4*)(p + 4);
    }
    if (tid < 64) {
        ef_s[tid][32] = 1.0f;
        ef_s[tid][33] = 0.0f;
        tgt_s[tid] = tgt[iperm[s0 + tid]];
    }
    __syncthreads();

    // MFMA phase (identical to proven R2 msg_mfma)
    const int wave  = tid >> 6;
    const int lane  = tid & 63;
    const int er    = lane & 15;
    const int g     = lane >> 4;
    const int e_loc = wave * 16 + er;
    const int h0    = (g & 1) * 8;
    const int fg    = g >> 1;

    float nb[8];
    #pragma unroll
    for (int j = 0; j < 8; ++j) nb[j] = neigh_s[e_loc][h0 + j];

    f32x4 acc0 = {0.f,0.f,0.f,0.f}, acc1 = acc0, acc2 = acc0, acc3 = acc0;
    const bf16x8* Bp = (const bf16x8*)WrB;
    #pragma unroll
    for (int ks = 0; ks < KSTEPS; ++ks) {
        const float a = ef_s[e_loc][2 * ks + fg];
        bf16x8 af;
        #pragma unroll
        for (int j = 0; j < 8; ++j) af[j] = (short)f2bfu(a * nb[j]);
        const bf16x8 b0 = Bp[(ks * 4 + 0) * 64 + lane];
        const bf16x8 b1 = Bp[(ks * 4 + 1) * 64 + lane];
        const bf16x8 b2 = Bp[(ks * 4 + 2) * 64 + lane];
        const bf16x8 b3 = Bp[(ks * 4 + 3) * 64 + lane];
        acc0 = __builtin_amdgcn_mfma_f32_16x16x32_bf16(af, b0, acc0, 0, 0, 0);
        acc1 = __builtin_amdgcn_mfma_f32_16x16x32_bf16(af, b1, acc1, 0, 0, 0);
        acc2 = __builtin_amdgcn_mfma_f32_16x16x32_bf16(af, b2, acc2, 0, 0, 0);
        acc3 = __builtin_amdgcn_mfma_f32_16x16x32_bf16(af, b3, acc3, 0, 0, 0);
    }

    // C tile -> LDS: row = edge-in-block, col = m
    #pragma unroll
    for (int r = 0; r < 4; ++r) {
        const int row = wave * 16 + g * 4 + r;
        msg_s[row][ 0 + er] = acc0[r];
        msg_s[row][16 + er] = acc1[r];
        msg_s[row][32 + er] = acc2[r];
        msg_s[row][48 + er] = acc3[r];
    }
    __syncthreads();

    // segmented reduce: wave q owns rows q*16..q*16+15, lane owns column c.
    // tgt_s is sorted; branch is wave-uniform (same rows for all 64 lanes).
    const int c = tid & 63;
    const int rbase = (tid >> 6) * 16;
    float run = msg_s[rbase][c];
    int   cur = tgt_s[rbase];
    #pragma unroll
    for (int r = 1; r < 16; ++r) {
        const int   tg = tgt_s[rbase + r];
        const float m  = msg_s[rbase + r][c];
        if (tg != cur) {
            atomicAdd(out + (size_t)cur * MSG + c, run);
            cur = tg;
            run = m;
        } else {
            run += m;
        }
    }
    atomicAdd(out + (size_t)cur * MSG + c, run);
}

// ---------------------------------------------------------------------------
// Tiny zero kernel for the fallback path.
// ---------------------------------------------------------------------------
__global__ __launch_bounds__(256) void zero_out(float* __restrict__ p, int n4) {
    const int i = blockIdx.x * 256 + threadIdx.x;
    if (i < n4) ((float4*)p)[i] = make_float4(0.f, 0.f, 0.f, 0.f);
}

// ---------------------------------------------------------------------------
// Fallback (R2 path): per-edge MFMA + fp32 atomics. Used if ws_size is small.
// ---------------------------------------------------------------------------
__global__ __launch_bounds__(256, 4) void msg_mfma(
    const float* __restrict__ ef, const int* __restrict__ src,
    const int* __restrict__ tgt, const float* __restrict__ hidden,
    const ushort* __restrict__ WrB, float* __restrict__ out)
{
    __shared__ float ef_s[64][36];
    __shared__ float neigh_s[64][20];
    __shared__ int   tgt_s[64];
    const int tid = threadIdx.x;
    const int e0  = blockIdx.x * 64;
    {
        const int e = tid >> 2, h4 = (tid & 3) * 4;
        const int s = src[e0 + e];
        *(float4*)&neigh_s[e][h4] = *(const float4*)(hidden + (size_t)s * HIDDEN + h4);
    }
    {
        const int e = tid >> 2, f8 = (tid & 3) * 8;
        const float* p = ef + (size_t)(e0 + e) * EDGE_FEAT + f8;
        *(float4*)&ef_s[e][f8]     = *(const float4*)(p);
        *(float4*)&ef_s[e][f8 + 4] = *(const float4*)(p + 4);
    }
    if (tid < 64) { ef_s[tid][32] = 1.0f; ef_s[tid][33] = 0.0f; tgt_s[tid] = tgt[e0 + tid]; }
    __syncthreads();
    const int wave = tid >> 6, lane = tid & 63;
    const int er = lane & 15, g = lane >> 4;
    const int e_loc = wave * 16 + er;
    const int h0 = (g & 1) * 8, fg = g >> 1;
    float nb[8];
    #pragma unroll
    for (int j = 0; j < 8; ++j) nb[j] = neigh_s[e_loc][h0 + j];
    f32x4 acc0 = {0.f,0.f,0.f,0.f}, acc1 = acc0, acc2 = acc0, acc3 = acc0;
    const bf16x8* Bp = (const bf16x8*)WrB;
    #pragma unroll
    for (int ks = 0; ks < KSTEPS; ++ks) {
        const float a = ef_s[e_loc][2 * ks + fg];
        bf16x8 af;
        #pragma unroll
        for (int j = 0; j < 8; ++j) af[j] = (short)f2bfu(a * nb[j]);
        const bf16x8 b0 = Bp[(ks * 4 + 0) * 64 + lane];
        const bf16x8 b1 = Bp[(ks * 4 + 1) * 64 + lane];
        const bf16x8 b2 = Bp[(ks * 4 + 2) * 64 + lane];
        const bf16x8 b3 = Bp[(ks * 4 + 3) * 64 + lane];
        acc0 = __builtin_amdgcn_mfma_f32_16x16x32_bf16(af, b0, acc0, 0, 0, 0);
        acc1 = __builtin_amdgcn_mfma_f32_16x16x32_bf16(af, b1, acc1, 0, 0, 0);
        acc2 = __builtin_amdgcn_mfma_f32_16x16x32_bf16(af, b2, acc2, 0, 0, 0);
        acc3 = __builtin_amdgcn_mfma_f32_16x16x32_bf16(af, b3, acc3, 0, 0, 0);
    }
    #pragma unroll
    for (int r = 0; r < 4; ++r) {
        const int t = tgt_s[wave * 16 + g * 4 + r];
        float* op = out + (size_t)t * MSG;
        atomicAdd(op +      er, acc0[r]);
        atomicAdd(op + 16 + er, acc1[r]);
        atomicAdd(op + 32 + er, acc2[r]);
        atomicAdd(op + 48 + er, acc3[r]);
    }
}

extern "C" void kernel_launch(void* const* d_in, const int* in_sizes, int n_in,
                              void* d_out, int out_size, void* d_ws, size_t ws_size,
                              hipStream_t stream) {
    // inputs: 0 node_features (unused), 1 edge_features, 2 edge_sources,
    //         3 edge_targets, 4 hidden, 5 initial (unused), 6 W, 7 b
    const float* ef     = (const float*)d_in[1];
    const int*   src    = (const int*)d_in[2];
    const int*   tgt    = (const int*)d_in[3];
    const float* hidden = (const float*)d_in[4];
    const float* W      = (const float*)d_in[6];
    const float* bias   = (const float*)d_in[7];
    float* out = (float*)d_out;
    char*  ws  = (char*)d_ws;

    // ws layout (16B aligned) — only index buffers now (~2.7 MB)
    const size_t o_wrb    = 0;            //     69,632 B
    const size_t o_starts = 69632;        //     40,004 B
    const size_t o_cnt    = 109648;       //     40,000 B
    const size_t o_rank   = 149648;       //  1,280,000 B
    const size_t o_iperm  = 1429648;      //  1,280,000 B
    const size_t need     = o_iperm + 1280000;   // ~2.71 MB

    ushort* WrB = (ushort*)(ws + o_wrb);
    const int n4 = out_size / 4;                         // float4 count (out is 640,000 f32)

    if (ws_size >= need) {
        int* starts = (int*)(ws + o_starts);
        int* cnt    = (int*)(ws + o_cnt);
        int* rank   = (int*)(ws + o_rank);
        int* iperm  = (int*)(ws + o_iperm);

        const int zb_cnt = 40;                           // ceil(10000/256)
        const int zb_out = (n4 + 255) / 256;             // 625
        zero_prep<<<KSTEPS + zb_cnt + zb_out, 256, 0, stream>>>(W, bias, WrB, cnt,
                                                                (float4*)out, n4);
        rank_kernel<<<(N_EDGES + 255) / 256, 256, 0, stream>>>(tgt, cnt, rank);
        scan_kernel<<<1, 1024, 0, stream>>>(cnt, starts);
        build_iperm<<<(N_EDGES + 255) / 256, 256, 0, stream>>>(tgt, rank, starts, iperm);
        fused_msg<<<N_EDGES / 64, 256, 0, stream>>>(iperm, tgt, src, ef, hidden, WrB, out);
    } else {
        // fallback: per-edge MFMA with fp32 atomics (proven R2 path, 89 us)
        zero_prep<<<KSTEPS, 256, 0, stream>>>(W, bias, WrB, nullptr, nullptr, 0);
        zero_out<<<(n4 + 255) / 256, 256, 0, stream>>>(out, n4);
        msg_mfma<<<N_EDGES / 64, 256, 0, stream>>>(ef, src, tgt, hidden, WrB, out);
    }
}

// Round 9
// 85.827 us; speedup vs baseline: 1.5838x; 1.0484x over previous
//
#include <hip/hip_runtime.h>
#include <hip/hip_bf16.h>

#define N_NODES 10000
#define N_EDGES 320000
#define HIDDEN 16
#define MSG 64
#define EDGE_FEAT 32
#define KSTEPS 17          // K = 544 = 512 (ef x hidden) + 16 (bias) + 16 (zero pad)
#define EPB 128            // edges per block (fused kernel)

typedef __attribute__((ext_vector_type(2))) _Float16 f16x2;
typedef __attribute__((ext_vector_type(4))) _Float16 f16x4;
typedef __attribute__((ext_vector_type(8))) _Float16 f16x8;
typedef __attribute__((ext_vector_type(4))) float    f32x4;

union H8 { f16x8 v; f16x2 p[4]; f16x4 q[2]; };

// ---------------------------------------------------------------------------
// Blocks [0,KSTEPS): pack WrB as f16 B-fragments (bias folded at k=512..527).
// Blocks [KSTEPS, KSTEPS+40): zero cnt.   Blocks [KSTEPS+40, ...): zero out.
// B-frag: lane holds k = ks*32 + (lane>>4)*8 + i, n = nt*16 + (lane&15).
// ---------------------------------------------------------------------------
__global__ void zero_prep(const float* __restrict__ W, const float* __restrict__ bias,
                          ushort* __restrict__ WrB, int* __restrict__ cnt,
                          float4* __restrict__ out4, int n4) {
    if (blockIdx.x < KSTEPS) {
        const int ks   = blockIdx.x;
        const int nt   = threadIdx.x >> 6;
        const int lane = threadIdx.x & 63;
        const int g    = lane >> 4;
        const int n    = nt * 16 + (lane & 15);
        ushort* dst = WrB + (((size_t)ks * 4 + nt) * 64 + lane) * 8;
        #pragma unroll
        for (int i = 0; i < 8; ++i) {
            const int k = ks * 32 + g * 8 + i;
            float v;
            if (k < 512)      v = W[(size_t)(k >> 4) * 1024 + n * 16 + (k & 15)];
            else if (k < 528) v = bias[n * 16 + (k - 512)];
            else              v = 0.0f;
            const _Float16 hv = (_Float16)v;
            dst[i] = *reinterpret_cast<const ushort*>(&hv);
        }
    } else if (blockIdx.x < KSTEPS + 40) {
        const int idx = (blockIdx.x - KSTEPS) * 256 + threadIdx.x;
        if (idx < N_NODES) cnt[idx] = 0;
    } else {
        const int i = (blockIdx.x - KSTEPS - 40) * 256 + threadIdx.x;
        if (i < n4) out4[i] = make_float4(0.f, 0.f, 0.f, 0.f);
    }
}

// ---------------------------------------------------------------------------
// rank[e] = atomicAdd(cnt[tgt[e]], 1)
// ---------------------------------------------------------------------------
__global__ __launch_bounds__(256) void rank_kernel(const int* __restrict__ tgt,
                                                   int* __restrict__ cnt,
                                                   int* __restrict__ rank) {
    const int e = blockIdx.x * 256 + threadIdx.x;
    if (e < N_EDGES) rank[e] = atomicAdd(&cnt[tgt[e]], 1);
}

// ---------------------------------------------------------------------------
// Exclusive scan of per-node counts -> starts. Wave-shuffle, 2 barriers.
// ---------------------------------------------------------------------------
__global__ __launch_bounds__(1024) void scan_kernel(const int* __restrict__ cnt,
                                                    int* __restrict__ starts) {
    __shared__ int wsum[16];
    __shared__ int wbase[16];
    const int tid  = threadIdx.x;
    const int lane = tid & 63;
    const int wv   = tid >> 6;
    int c[10];
    int s = 0;
    #pragma unroll
    for (int j = 0; j < 10; ++j) {
        const int idx = tid * 10 + j;
        c[j] = (idx < N_NODES) ? cnt[idx] : 0;
        s += c[j];
    }
    int v = s;
    #pragma unroll
    for (int d = 1; d < 64; d <<= 1) {
        const int u = __shfl_up(v, d);
        if (lane >= d) v += u;
    }
    if (lane == 63) wsum[wv] = v;
    __syncthreads();
    if (tid < 16) {
        const int w = wsum[tid];
        int iv = w;
        #pragma unroll
        for (int d = 1; d < 16; d <<= 1) {
            const int u = __shfl_up(iv, d);
            if (tid >= d) iv += u;
        }
        wbase[tid] = iv - w;
    }
    __syncthreads();
    int running = wbase[wv] + (v - s);
    #pragma unroll
    for (int j = 0; j < 10; ++j) {
        const int idx = tid * 10 + j;
        if (idx < N_NODES) starts[idx] = running;
        running += c[j];
    }
    if (tid == 1023) starts[N_NODES] = N_EDGES;
}

// ---------------------------------------------------------------------------
// iperm[starts[tgt[e]] + rank[e]] = e
// ---------------------------------------------------------------------------
__global__ __launch_bounds__(256) void build_iperm(
    const int* __restrict__ tgt, const int* __restrict__ rank,
    const int* __restrict__ starts, int* __restrict__ iperm) {
    const int e = blockIdx.x * 256 + threadIdx.x;
    if (e < N_EDGES) iperm[starts[tgt[e]] + rank[e]] = e;
}

// ---------------------------------------------------------------------------
// Fused: 128 TARGET-SORTED edges per block (4 waves, 2 row-tiles per wave so
// each B-fragment load feeds 8 MFMAs). f16 pipeline: ef/neigh converted once
// in gather; af build = 1 ds_read_u16 + 4 v_pk_mul_f16 per tile per K-step.
// Epilogue: LDS message tile + wave-uniform run-length segmented reduce.
// ---------------------------------------------------------------------------
__global__ __launch_bounds__(256) void fused_msg(
    const int*    __restrict__ iperm,
    const int*    __restrict__ tgt,
    const int*    __restrict__ src,
    const float*  __restrict__ ef,
    const float*  __restrict__ hidden,
    const ushort* __restrict__ WrB,
    float*        __restrict__ out)
{
    __shared__ _Float16 ef_h[EPB][36];   // cols 0..31 ef, 32 = 1.0 (bias), 33 = 0.0
    __shared__ _Float16 nb_h[EPB][16];   // gathered hidden rows (f16)
    __shared__ int      tgt_s[EPB];
    __shared__ float    msg_s[EPB][68];  // message tile, padded

    const int tid = threadIdx.x;
    const int s0  = blockIdx.x * EPB;

    // ---- gather: 2 threads per sorted slot ----
    {
        const int sl   = tid >> 1;
        const int half = tid & 1;
        const int e    = iperm[s0 + sl];
        const int sn   = src[e];

        const float4* ep = (const float4*)(ef + (size_t)e * EDGE_FEAT + half * 16);
        const float4 v0 = ep[0], v1 = ep[1], v2 = ep[2], v3 = ep[3];
        _Float16* dst = &ef_h[sl][half * 16];
        *(f16x4*)(dst + 0)  = f16x4{(_Float16)v0.x, (_Float16)v0.y, (_Float16)v0.z, (_Float16)v0.w};
        *(f16x4*)(dst + 4)  = f16x4{(_Float16)v1.x, (_Float16)v1.y, (_Float16)v1.z, (_Float16)v1.w};
        *(f16x4*)(dst + 8)  = f16x4{(_Float16)v2.x, (_Float16)v2.y, (_Float16)v2.z, (_Float16)v2.w};
        *(f16x4*)(dst + 12) = f16x4{(_Float16)v3.x, (_Float16)v3.y, (_Float16)v3.z, (_Float16)v3.w};

        const float4* hp = (const float4*)(hidden + (size_t)sn * HIDDEN + half * 8);
        const float4 h0 = hp[0], h1 = hp[1];
        *(f16x8*)&nb_h[sl][half * 8] =
            f16x8{(_Float16)h0.x, (_Float16)h0.y, (_Float16)h0.z, (_Float16)h0.w,
                  (_Float16)h1.x, (_Float16)h1.y, (_Float16)h1.z, (_Float16)h1.w};

        if (half) {                       // cols 32..35: bias feature + pad
            ef_h[sl][32] = (_Float16)1.0f;
            ef_h[sl][33] = (_Float16)0.0f;
            ef_h[sl][34] = (_Float16)0.0f;
            ef_h[sl][35] = (_Float16)0.0f;
        } else {
            tgt_s[sl] = tgt[e];
        }
    }
    __syncthreads();

    // ---- MFMA phase: wave handles 32 edges as two 16-row tiles ----
    const int wave = tid >> 6;
    const int lane = tid & 63;
    const int er   = lane & 15;
    const int g    = lane >> 4;
    const int eA   = wave * 32 + er;       // tile A edge row
    const int eB   = eA + 16;              // tile B edge row
    const int hoff = (g & 1) * 8;
    const int fg   = g >> 1;

    H8 nbA, nbB;
    nbA.v = *(const f16x8*)&nb_h[eA][hoff];
    nbB.v = *(const f16x8*)&nb_h[eB][hoff];

    f32x4 aA0 = {0.f,0.f,0.f,0.f}, aA1 = aA0, aA2 = aA0, aA3 = aA0;
    f32x4 aB0 = aA0, aB1 = aA0, aB2 = aA0, aB3 = aA0;
    const f16x8* Bp = (const f16x8*)WrB;

    #pragma unroll
    for (int ks = 0; ks < KSTEPS; ++ks) {
        const f16x8 b0 = Bp[(ks * 4 + 0) * 64 + lane];
        const f16x8 b1 = Bp[(ks * 4 + 1) * 64 + lane];
        const f16x8 b2 = Bp[(ks * 4 + 2) * 64 + lane];
        const f16x8 b3 = Bp[(ks * 4 + 3) * 64 + lane];

        const _Float16 a_A = ef_h[eA][2 * ks + fg];
        const _Float16 a_B = ef_h[eB][2 * ks + fg];
        const f16x2 avA = {a_A, a_A};
        const f16x2 avB = {a_B, a_B};
        H8 afA, afB;
        #pragma unroll
        for (int q = 0; q < 4; ++q) {
            afA.p[q] = avA * nbA.p[q];     // v_pk_mul_f16
            afB.p[q] = avB * nbB.p[q];
        }
        aA0 = __builtin_amdgcn_mfma_f32_16x16x32_f16(afA.v, b0, aA0, 0, 0, 0);
        aA1 = __builtin_amdgcn_mfma_f32_16x16x32_f16(afA.v, b1, aA1, 0, 0, 0);
        aA2 = __builtin_amdgcn_mfma_f32_16x16x32_f16(afA.v, b2, aA2, 0, 0, 0);
        aA3 = __builtin_amdgcn_mfma_f32_16x16x32_f16(afA.v, b3, aA3, 0, 0, 0);
        aB0 = __builtin_amdgcn_mfma_f32_16x16x32_f16(afB.v, b0, aB0, 0, 0, 0);
        aB1 = __builtin_amdgcn_mfma_f32_16x16x32_f16(afB.v, b1, aB1, 0, 0, 0);
        aB2 = __builtin_amdgcn_mfma_f32_16x16x32_f16(afB.v, b2, aB2, 0, 0, 0);
        aB3 = __builtin_amdgcn_mfma_f32_16x16x32_f16(afB.v, b3, aB3, 0, 0, 0);
    }

    // ---- C tiles -> LDS: row = edge-in-block, col = m ----
    #pragma unroll
    for (int r = 0; r < 4; ++r) {
        const int rowA = wave * 32 + g * 4 + r;
        msg_s[rowA][ 0 + er] = aA0[r];
        msg_s[rowA][16 + er] = aA1[r];
        msg_s[rowA][32 + er] = aA2[r];
        msg_s[rowA][48 + er] = aA3[r];
        const int rowB = rowA + 16;
        msg_s[rowB][ 0 + er] = aB0[r];
        msg_s[rowB][16 + er] = aB1[r];
        msg_s[rowB][32 + er] = aB2[r];
        msg_s[rowB][48 + er] = aB3[r];
    }
    __syncthreads();

    // ---- segmented reduce: wave w owns rows w*32..w*32+31, lane owns col ----
    const int c = tid & 63;
    const int rbase = (tid >> 6) * 32;
    float run = msg_s[rbase][c];
    int   cur = tgt_s[rbase];
    #pragma unroll
    for (int r = 1; r < 32; ++r) {
        const int   tg = tgt_s[rbase + r];
        const float m  = msg_s[rbase + r][c];
        if (tg != cur) {
            atomicAdd(out + (size_t)cur * MSG + c, run);
            cur = tg;
            run = m;
        } else {
            run += m;
        }
    }
    atomicAdd(out + (size_t)cur * MSG + c, run);
}

// ---------------------------------------------------------------------------
// Tiny zero kernel for the fallback path.
// ---------------------------------------------------------------------------
__global__ __launch_bounds__(256) void zero_out(float* __restrict__ p, int n4) {
    const int i = blockIdx.x * 256 + threadIdx.x;
    if (i < n4) ((float4*)p)[i] = make_float4(0.f, 0.f, 0.f, 0.f);
}

// ---------------------------------------------------------------------------
// Fallback (R2 structure, f16): per-edge MFMA + fp32 atomics (small ws only).
// ---------------------------------------------------------------------------
__global__ __launch_bounds__(256, 4) void msg_mfma(
    const float* __restrict__ ef, const int* __restrict__ src,
    const int* __restrict__ tgt, const float* __restrict__ hidden,
    const ushort* __restrict__ WrB, float* __restrict__ out)
{
    __shared__ float ef_s[64][36];
    __shared__ float neigh_s[64][20];
    __shared__ int   tgt_s[64];
    const int tid = threadIdx.x;
    const int e0  = blockIdx.x * 64;
    {
        const int e = tid >> 2, h4 = (tid & 3) * 4;
        const int s = src[e0 + e];
        *(float4*)&neigh_s[e][h4] = *(const float4*)(hidden + (size_t)s * HIDDEN + h4);
    }
    {
        const int e = tid >> 2, f8 = (tid & 3) * 8;
        const float* p = ef + (size_t)(e0 + e) * EDGE_FEAT + f8;
        *(float4*)&ef_s[e][f8]     = *(const float4*)(p);
        *(float4*)&ef_s[e][f8 + 4] = *(const float4*)(p + 4);
    }
    if (tid < 64) { ef_s[tid][32] = 1.0f; ef_s[tid][33] = 0.0f; tgt_s[tid] = tgt[e0 + tid]; }
    __syncthreads();
    const int wave = tid >> 6, lane = tid & 63;
    const int er = lane & 15, g = lane >> 4;
    const int e_loc = wave * 16 + er;
    const int h0 = (g & 1) * 8, fg = g >> 1;
    float nb[8];
    #pragma unroll
    for (int j = 0; j < 8; ++j) nb[j] = neigh_s[e_loc][h0 + j];
    f32x4 acc0 = {0.f,0.f,0.f,0.f}, acc1 = acc0, acc2 = acc0, acc3 = acc0;
    const f16x8* Bp = (const f16x8*)WrB;
    #pragma unroll
    for (int ks = 0; ks < KSTEPS; ++ks) {
        const float a = ef_s[e_loc][2 * ks + fg];
        f16x8 af;
        #pragma unroll
        for (int j = 0; j < 8; ++j) af[j] = (_Float16)(a * nb[j]);
        const f16x8 b0 = Bp[(ks * 4 + 0) * 64 + lane];
        const f16x8 b1 = Bp[(ks * 4 + 1) * 64 + lane];
        const f16x8 b2 = Bp[(ks * 4 + 2) * 64 + lane];
        const f16x8 b3 = Bp[(ks * 4 + 3) * 64 + lane];
        acc0 = __builtin_amdgcn_mfma_f32_16x16x32_f16(af, b0, acc0, 0, 0, 0);
        acc1 = __builtin_amdgcn_mfma_f32_16x16x32_f16(af, b1, acc1, 0, 0, 0);
        acc2 = __builtin_amdgcn_mfma_f32_16x16x32_f16(af, b2, acc2, 0, 0, 0);
        acc3 = __builtin_amdgcn_mfma_f32_16x16x32_f16(af, b3, acc3, 0, 0, 0);
    }
    #pragma unroll
    for (int r = 0; r < 4; ++r) {
        const int t = tgt_s[wave * 16 + g * 4 + r];
        float* op = out + (size_t)t * MSG;
        atomicAdd(op +      er, acc0[r]);
        atomicAdd(op + 16 + er, acc1[r]);
        atomicAdd(op + 32 + er, acc2[r]);
        atomicAdd(op + 48 + er, acc3[r]);
    }
}

extern "C" void kernel_launch(void* const* d_in, const int* in_sizes, int n_in,
                              void* d_out, int out_size, void* d_ws, size_t ws_size,
                              hipStream_t stream) {
    // inputs: 0 node_features (unused), 1 edge_features, 2 edge_sources,
    //         3 edge_targets, 4 hidden, 5 initial (unused), 6 W, 7 b
    const float* ef     = (const float*)d_in[1];
    const int*   src    = (const int*)d_in[2];
    const int*   tgt    = (const int*)d_in[3];
    const float* hidden = (const float*)d_in[4];
    const float* W      = (const float*)d_in[6];
    const float* bias   = (const float*)d_in[7];
    float* out = (float*)d_out;
    char*  ws  = (char*)d_ws;

    // ws layout (16B aligned) — index buffers only (~2.7 MB)
    const size_t o_wrb    = 0;            //     69,632 B
    const size_t o_starts = 69632;        //     40,004 B
    const size_t o_cnt    = 109648;       //     40,000 B
    const size_t o_rank   = 149648;       //  1,280,000 B
    const size_t o_iperm  = 1429648;      //  1,280,000 B
    const size_t need     = o_iperm + 1280000;   // ~2.71 MB

    ushort* WrB = (ushort*)(ws + o_wrb);
    const int n4 = out_size / 4;

    if (ws_size >= need) {
        int* starts = (int*)(ws + o_starts);
        int* cnt    = (int*)(ws + o_cnt);
        int* rank   = (int*)(ws + o_rank);
        int* iperm  = (int*)(ws + o_iperm);

        const int zb_cnt = 40;
        const int zb_out = (n4 + 255) / 256;
        zero_prep<<<KSTEPS + zb_cnt + zb_out, 256, 0, stream>>>(W, bias, WrB, cnt,
                                                                (float4*)out, n4);
        rank_kernel<<<(N_EDGES + 255) / 256, 256, 0, stream>>>(tgt, cnt, rank);
        scan_kernel<<<1, 1024, 0, stream>>>(cnt, starts);
        build_iperm<<<(N_EDGES + 255) / 256, 256, 0, stream>>>(tgt, rank, starts, iperm);
        fused_msg<<<N_EDGES / EPB, 256, 0, stream>>>(iperm, tgt, src, ef, hidden, WrB, out);
    } else {
        zero_prep<<<KSTEPS, 256, 0, stream>>>(W, bias, WrB, nullptr, nullptr, 0);
        zero_out<<<(n4 + 255) / 256, 256, 0, stream>>>(out, n4);
        msg_mfma<<<N_EDGES / 64, 256, 0, stream>>>(ef, src, tgt, hidden, WrB, out);
    }
}

// Round 10
// 76.639 us; speedup vs baseline: 1.7737x; 1.1199x over previous
//
#include <hip/hip_runtime.h>
#include <hip/hip_bf16.h>

#define N_NODES 10000
#define N_EDGES 320000
#define HIDDEN 16
#define MSG 64
#define EDGE_FEAT 32
#define KSTEPS 17          // K = 544 = 512 (ef x hidden) + 16 (bias) + 16 (zero pad)
#define EPB 128            // edges per block (fused kernel)

typedef __attribute__((ext_vector_type(2))) _Float16 f16x2;
typedef __attribute__((ext_vector_type(4))) _Float16 f16x4;
typedef __attribute__((ext_vector_type(8))) _Float16 f16x8;
typedef __attribute__((ext_vector_type(4))) float    f32x4;

union H8 { f16x8 v; f16x2 p[4]; f16x4 q[2]; };

// ---------------------------------------------------------------------------
// Blocks [0,KSTEPS): pack WrB as f16 B-fragments (bias folded at k=512..527).
// Blocks [KSTEPS, KSTEPS+40): zero cnt.   Blocks [KSTEPS+40, ...): zero out.
// B-frag: lane holds k = ks*32 + (lane>>4)*8 + i, n = nt*16 + (lane&15).
// ---------------------------------------------------------------------------
__global__ void zero_prep(const float* __restrict__ W, const float* __restrict__ bias,
                          ushort* __restrict__ WrB, int* __restrict__ cnt,
                          float4* __restrict__ out4, int n4) {
    if (blockIdx.x < KSTEPS) {
        const int ks   = blockIdx.x;
        const int nt   = threadIdx.x >> 6;
        const int lane = threadIdx.x & 63;
        const int g    = lane >> 4;
        const int n    = nt * 16 + (lane & 15);
        ushort* dst = WrB + (((size_t)ks * 4 + nt) * 64 + lane) * 8;
        #pragma unroll
        for (int i = 0; i < 8; ++i) {
            const int k = ks * 32 + g * 8 + i;
            float v;
            if (k < 512)      v = W[(size_t)(k >> 4) * 1024 + n * 16 + (k & 15)];
            else if (k < 528) v = bias[n * 16 + (k - 512)];
            else              v = 0.0f;
            const _Float16 hv = (_Float16)v;
            dst[i] = *reinterpret_cast<const ushort*>(&hv);
        }
    } else if (blockIdx.x < KSTEPS + 40) {
        const int idx = (blockIdx.x - KSTEPS) * 256 + threadIdx.x;
        if (idx < N_NODES) cnt[idx] = 0;
    } else {
        const int i = (blockIdx.x - KSTEPS - 40) * 256 + threadIdx.x;
        if (i < n4) out4[i] = make_float4(0.f, 0.f, 0.f, 0.f);
    }
}

// ---------------------------------------------------------------------------
// rank[e] = atomicAdd(cnt[tgt[e]], 1)
// ---------------------------------------------------------------------------
__global__ __launch_bounds__(256) void rank_kernel(const int* __restrict__ tgt,
                                                   int* __restrict__ cnt,
                                                   int* __restrict__ rank) {
    const int e = blockIdx.x * 256 + threadIdx.x;
    if (e < N_EDGES) rank[e] = atomicAdd(&cnt[tgt[e]], 1);
}

// ---------------------------------------------------------------------------
// Exclusive scan of per-node counts -> starts. Wave-shuffle, 2 barriers.
// ---------------------------------------------------------------------------
__global__ __launch_bounds__(1024) void scan_kernel(const int* __restrict__ cnt,
                                                    int* __restrict__ starts) {
    __shared__ int wsum[16];
    __shared__ int wbase[16];
    const int tid  = threadIdx.x;
    const int lane = tid & 63;
    const int wv   = tid >> 6;
    int c[10];
    int s = 0;
    #pragma unroll
    for (int j = 0; j < 10; ++j) {
        const int idx = tid * 10 + j;
        c[j] = (idx < N_NODES) ? cnt[idx] : 0;
        s += c[j];
    }
    int v = s;
    #pragma unroll
    for (int d = 1; d < 64; d <<= 1) {
        const int u = __shfl_up(v, d);
        if (lane >= d) v += u;
    }
    if (lane == 63) wsum[wv] = v;
    __syncthreads();
    if (tid < 16) {
        const int w = wsum[tid];
        int iv = w;
        #pragma unroll
        for (int d = 1; d < 16; d <<= 1) {
            const int u = __shfl_up(iv, d);
            if (tid >= d) iv += u;
        }
        wbase[tid] = iv - w;
    }
    __syncthreads();
    int running = wbase[wv] + (v - s);
    #pragma unroll
    for (int j = 0; j < 10; ++j) {
        const int idx = tid * 10 + j;
        if (idx < N_NODES) starts[idx] = running;
        running += c[j];
    }
    if (tid == 1023) starts[N_NODES] = N_EDGES;
}

// ---------------------------------------------------------------------------
// Sorted edge descriptors: edesc[starts[tgt[e]]+rank[e]] = {e, src[e], tgt[e], 0}.
// All reads coalesced; one 16B scattered fire-and-forget store per edge.
// Lets the fused gather read ONE coalesced 16B instead of 3 random 4B loads.
// ---------------------------------------------------------------------------
__global__ __launch_bounds__(256) void build_desc(
    const int* __restrict__ tgt, const int* __restrict__ rank,
    const int* __restrict__ starts, const int* __restrict__ src,
    int4* __restrict__ edesc) {
    const int e = blockIdx.x * 256 + threadIdx.x;
    if (e < N_EDGES) {
        const int t = tgt[e];
        edesc[starts[t] + rank[e]] = make_int4(e, src[e], t, 0);
    }
}

// ---------------------------------------------------------------------------
// Fused: 128 TARGET-SORTED edges per block (4 waves x 2 row-tiles). f16
// pipeline. LDS trimmed to ~31KB (msg tile f16) -> 5 blocks/CU.
// Epilogue: f16 LDS message tile + wave-uniform run-length segmented reduce
// (fp32 accumulation, fp32 atomics).
// ---------------------------------------------------------------------------
__global__ __launch_bounds__(256, 5) void fused_msg(
    const int4*   __restrict__ edesc,
    const float*  __restrict__ ef,
    const float*  __restrict__ hidden,
    const ushort* __restrict__ WrB,
    float*        __restrict__ out)
{
    __shared__ _Float16 ef_h[EPB][36];   // cols 0..31 ef, 32 = 1.0 (bias), 33..35 = 0
    __shared__ _Float16 nb_h[EPB][16];   // gathered hidden rows (f16)
    __shared__ int      tgt_s[EPB];
    __shared__ _Float16 msg_h[EPB][68];  // message tile (f16), padded

    const int tid = threadIdx.x;
    const int s0  = blockIdx.x * EPB;

    // ---- gather: 2 threads per sorted slot; descriptor is coalesced 16B ----
    {
        const int sl = tid >> 1;
        const int hf = tid & 1;
        const int4 d = edesc[s0 + sl];
        const int e  = d.x;
        const int sn = d.y;

        const float4* ep = (const float4*)(ef + (size_t)e * EDGE_FEAT + hf * 16);
        const float4 v0 = ep[0], v1 = ep[1], v2 = ep[2], v3 = ep[3];
        _Float16* dst = &ef_h[sl][hf * 16];
        *(f16x4*)(dst + 0)  = f16x4{(_Float16)v0.x, (_Float16)v0.y, (_Float16)v0.z, (_Float16)v0.w};
        *(f16x4*)(dst + 4)  = f16x4{(_Float16)v1.x, (_Float16)v1.y, (_Float16)v1.z, (_Float16)v1.w};
        *(f16x4*)(dst + 8)  = f16x4{(_Float16)v2.x, (_Float16)v2.y, (_Float16)v2.z, (_Float16)v2.w};
        *(f16x4*)(dst + 12) = f16x4{(_Float16)v3.x, (_Float16)v3.y, (_Float16)v3.z, (_Float16)v3.w};

        const float4* hp = (const float4*)(hidden + (size_t)sn * HIDDEN + hf * 8);
        const float4 h0 = hp[0], h1 = hp[1];
        *(f16x8*)&nb_h[sl][hf * 8] =
            f16x8{(_Float16)h0.x, (_Float16)h0.y, (_Float16)h0.z, (_Float16)h0.w,
                  (_Float16)h1.x, (_Float16)h1.y, (_Float16)h1.z, (_Float16)h1.w};

        if (hf) {
            ef_h[sl][32] = (_Float16)1.0f;
            ef_h[sl][33] = (_Float16)0.0f;
            ef_h[sl][34] = (_Float16)0.0f;
            ef_h[sl][35] = (_Float16)0.0f;
        } else {
            tgt_s[sl] = d.z;
        }
    }
    __syncthreads();

    // ---- MFMA phase: wave handles 32 edges as two 16-row tiles ----
    const int wave = tid >> 6;
    const int lane = tid & 63;
    const int er   = lane & 15;
    const int g    = lane >> 4;
    const int eA   = wave * 32 + er;
    const int eB   = eA + 16;
    const int hoff = (g & 1) * 8;
    const int fg   = g >> 1;

    H8 nbA, nbB;
    nbA.v = *(const f16x8*)&nb_h[eA][hoff];
    nbB.v = *(const f16x8*)&nb_h[eB][hoff];

    f32x4 aA0 = {0.f,0.f,0.f,0.f}, aA1 = aA0, aA2 = aA0, aA3 = aA0;
    f32x4 aB0 = aA0, aB1 = aA0, aB2 = aA0, aB3 = aA0;
    const f16x8* Bp = (const f16x8*)WrB;

    #pragma unroll
    for (int ks = 0; ks < KSTEPS; ++ks) {
        const f16x8 b0 = Bp[(ks * 4 + 0) * 64 + lane];
        const f16x8 b1 = Bp[(ks * 4 + 1) * 64 + lane];
        const f16x8 b2 = Bp[(ks * 4 + 2) * 64 + lane];
        const f16x8 b3 = Bp[(ks * 4 + 3) * 64 + lane];

        const _Float16 a_A = ef_h[eA][2 * ks + fg];
        const _Float16 a_B = ef_h[eB][2 * ks + fg];
        const f16x2 avA = {a_A, a_A};
        const f16x2 avB = {a_B, a_B};
        H8 afA, afB;
        #pragma unroll
        for (int q = 0; q < 4; ++q) {
            afA.p[q] = avA * nbA.p[q];     // v_pk_mul_f16
            afB.p[q] = avB * nbB.p[q];
        }
        aA0 = __builtin_amdgcn_mfma_f32_16x16x32_f16(afA.v, b0, aA0, 0, 0, 0);
        aA1 = __builtin_amdgcn_mfma_f32_16x16x32_f16(afA.v, b1, aA1, 0, 0, 0);
        aA2 = __builtin_amdgcn_mfma_f32_16x16x32_f16(afA.v, b2, aA2, 0, 0, 0);
        aA3 = __builtin_amdgcn_mfma_f32_16x16x32_f16(afA.v, b3, aA3, 0, 0, 0);
        aB0 = __builtin_amdgcn_mfma_f32_16x16x32_f16(afB.v, b0, aB0, 0, 0, 0);
        aB1 = __builtin_amdgcn_mfma_f32_16x16x32_f16(afB.v, b1, aB1, 0, 0, 0);
        aB2 = __builtin_amdgcn_mfma_f32_16x16x32_f16(afB.v, b2, aB2, 0, 0, 0);
        aB3 = __builtin_amdgcn_mfma_f32_16x16x32_f16(afB.v, b3, aB3, 0, 0, 0);
    }

    // ---- C tiles -> LDS (f16): row = edge-in-block, col = m ----
    #pragma unroll
    for (int r = 0; r < 4; ++r) {
        const int rowA = wave * 32 + g * 4 + r;
        msg_h[rowA][ 0 + er] = (_Float16)aA0[r];
        msg_h[rowA][16 + er] = (_Float16)aA1[r];
        msg_h[rowA][32 + er] = (_Float16)aA2[r];
        msg_h[rowA][48 + er] = (_Float16)aA3[r];
        const int rowB = rowA + 16;
        msg_h[rowB][ 0 + er] = (_Float16)aB0[r];
        msg_h[rowB][16 + er] = (_Float16)aB1[r];
        msg_h[rowB][32 + er] = (_Float16)aB2[r];
        msg_h[rowB][48 + er] = (_Float16)aB3[r];
    }
    __syncthreads();

    // ---- segmented reduce: wave w owns rows w*32..w*32+31, lane owns col ----
    const int c = tid & 63;
    const int rbase = (tid >> 6) * 32;
    float run = (float)msg_h[rbase][c];
    int   cur = tgt_s[rbase];
    #pragma unroll
    for (int r = 1; r < 32; ++r) {
        const int   tg = tgt_s[rbase + r];
        const float m  = (float)msg_h[rbase + r][c];
        if (tg != cur) {
            atomicAdd(out + (size_t)cur * MSG + c, run);
            cur = tg;
            run = m;
        } else {
            run += m;
        }
    }
    atomicAdd(out + (size_t)cur * MSG + c, run);
}

// ---------------------------------------------------------------------------
// Tiny zero kernel for the fallback path.
// ---------------------------------------------------------------------------
__global__ __launch_bounds__(256) void zero_out(float* __restrict__ p, int n4) {
    const int i = blockIdx.x * 256 + threadIdx.x;
    if (i < n4) ((float4*)p)[i] = make_float4(0.f, 0.f, 0.f, 0.f);
}

// ---------------------------------------------------------------------------
// Fallback (R2 structure, f16): per-edge MFMA + fp32 atomics (small ws only).
// ---------------------------------------------------------------------------
__global__ __launch_bounds__(256, 4) void msg_mfma(
    const float* __restrict__ ef, const int* __restrict__ src,
    const int* __restrict__ tgt, const float* __restrict__ hidden,
    const ushort* __restrict__ WrB, float* __restrict__ out)
{
    __shared__ float ef_s[64][36];
    __shared__ float neigh_s[64][20];
    __shared__ int   tgt_s[64];
    const int tid = threadIdx.x;
    const int e0  = blockIdx.x * 64;
    {
        const int e = tid >> 2, h4 = (tid & 3) * 4;
        const int s = src[e0 + e];
        *(float4*)&neigh_s[e][h4] = *(const float4*)(hidden + (size_t)s * HIDDEN + h4);
    }
    {
        const int e = tid >> 2, f8 = (tid & 3) * 8;
        const float* p = ef + (size_t)(e0 + e) * EDGE_FEAT + f8;
        *(float4*)&ef_s[e][f8]     = *(const float4*)(p);
        *(float4*)&ef_s[e][f8 + 4] = *(const float4*)(p + 4);
    }
    if (tid < 64) { ef_s[tid][32] = 1.0f; ef_s[tid][33] = 0.0f; tgt_s[tid] = tgt[e0 + tid]; }
    __syncthreads();
    const int wave = tid >> 6, lane = tid & 63;
    const int er = lane & 15, g = lane >> 4;
    const int e_loc = wave * 16 + er;
    const int h0 = (g & 1) * 8, fg = g >> 1;
    float nb[8];
    #pragma unroll
    for (int j = 0; j < 8; ++j) nb[j] = neigh_s[e_loc][h0 + j];
    f32x4 acc0 = {0.f,0.f,0.f,0.f}, acc1 = acc0, acc2 = acc0, acc3 = acc0;
    const f16x8* Bp = (const f16x8*)WrB;
    #pragma unroll
    for (int ks = 0; ks < KSTEPS; ++ks) {
        const float a = ef_s[e_loc][2 * ks + fg];
        f16x8 af;
        #pragma unroll
        for (int j = 0; j < 8; ++j) af[j] = (_Float16)(a * nb[j]);
        const f16x8 b0 = Bp[(ks * 4 + 0) * 64 + lane];
        const f16x8 b1 = Bp[(ks * 4 + 1) * 64 + lane];
        const f16x8 b2 = Bp[(ks * 4 + 2) * 64 + lane];
        const f16x8 b3 = Bp[(ks * 4 + 3) * 64 + lane];
        acc0 = __builtin_amdgcn_mfma_f32_16x16x32_f16(af, b0, acc0, 0, 0, 0);
        acc1 = __builtin_amdgcn_mfma_f32_16x16x32_f16(af, b1, acc1, 0, 0, 0);
        acc2 = __builtin_amdgcn_mfma_f32_16x16x32_f16(af, b2, acc2, 0, 0, 0);
        acc3 = __builtin_amdgcn_mfma_f32_16x16x32_f16(af, b3, acc3, 0, 0, 0);
    }
    #pragma unroll
    for (int r = 0; r < 4; ++r) {
        const int t = tgt_s[wave * 16 + g * 4 + r];
        float* op = out + (size_t)t * MSG;
        atomicAdd(op +      er, acc0[r]);
        atomicAdd(op + 16 + er, acc1[r]);
        atomicAdd(op + 32 + er, acc2[r]);
        atomicAdd(op + 48 + er, acc3[r]);
    }
}

extern "C" void kernel_launch(void* const* d_in, const int* in_sizes, int n_in,
                              void* d_out, int out_size, void* d_ws, size_t ws_size,
                              hipStream_t stream) {
    // inputs: 0 node_features (unused), 1 edge_features, 2 edge_sources,
    //         3 edge_targets, 4 hidden, 5 initial (unused), 6 W, 7 b
    const float* ef     = (const float*)d_in[1];
    const int*   src    = (const int*)d_in[2];
    const int*   tgt    = (const int*)d_in[3];
    const float* hidden = (const float*)d_in[4];
    const float* W      = (const float*)d_in[6];
    const float* bias   = (const float*)d_in[7];
    float* out = (float*)d_out;
    char*  ws  = (char*)d_ws;

    // ws layout (16B aligned) — ~6.6 MB
    const size_t o_wrb    = 0;            //     69,632 B
    const size_t o_starts = 69632;        //     40,004 B
    const size_t o_cnt    = 109648;       //     40,000 B
    const size_t o_rank   = 149648;       //  1,280,000 B
    const size_t o_desc   = 1429648;      //  5,120,000 B (int4 per edge)
    const size_t need     = o_desc + (size_t)N_EDGES * 16;

    ushort* WrB = (ushort*)(ws + o_wrb);
    const int n4 = out_size / 4;

    if (ws_size >= need) {
        int*  starts = (int*)(ws + o_starts);
        int*  cnt    = (int*)(ws + o_cnt);
        int*  rank   = (int*)(ws + o_rank);
        int4* edesc  = (int4*)(ws + o_desc);

        const int zb_cnt = 40;
        const int zb_out = (n4 + 255) / 256;
        zero_prep<<<KSTEPS + zb_cnt + zb_out, 256, 0, stream>>>(W, bias, WrB, cnt,
                                                                (float4*)out, n4);
        rank_kernel<<<(N_EDGES + 255) / 256, 256, 0, stream>>>(tgt, cnt, rank);
        scan_kernel<<<1, 1024, 0, stream>>>(cnt, starts);
        build_desc<<<(N_EDGES + 255) / 256, 256, 0, stream>>>(tgt, rank, starts, src, edesc);
        fused_msg<<<N_EDGES / EPB, 256, 0, stream>>>(edesc, ef, hidden, WrB, out);
    } else {
        zero_prep<<<KSTEPS, 256, 0, stream>>>(W, bias, WrB, nullptr, nullptr, 0);
        zero_out<<<(n4 + 255) / 256, 256, 0, stream>>>(out, n4);
        msg_mfma<<<N_EDGES / 64, 256, 0, stream>>>(ef, src, tgt, hidden, WrB, out);
    }
}